// Round 1
// baseline (459.686 us; speedup 1.0000x reference)
//
#include <hip/hip_runtime.h>

// Problem constants (from reference)
constexpr int B = 8;
constexpr int N = 4096;
constexpr int E = 131072;     // 2^17
constexpr int C = 256;
constexpr int BN_TOT = B * N; // 32768

// ---------------------------------------------------------------------------
// K1: count in-degree per (graph, node)
__global__ __launch_bounds__(256) void count_kernel(const int* __restrict__ ei,
                                                    int* __restrict__ counts) {
    int idx = blockIdx.x * 256 + threadIdx.x;   // [0, B*E)
    int b = idx >> 17;                          // / E
    int e = idx & (E - 1);
    int dst = ei[(size_t)b * 2 * E + E + e];
    atomicAdd(&counts[b * N + dst], 1);
}

// ---------------------------------------------------------------------------
// K2: per-graph exclusive scan of counts -> CSR offsets; also dinv = rsqrt(deg)
__global__ __launch_bounds__(1024) void scan_kernel(const int* __restrict__ counts,
                                                    int* __restrict__ offs,
                                                    float* __restrict__ dinv) {
    __shared__ int lds[1024];
    int b = blockIdx.x, t = threadIdx.x;
    int base = b * N + t * 4;
    int c0 = counts[base + 0];
    int c1 = counts[base + 1];
    int c2 = counts[base + 2];
    int c3 = counts[base + 3];
    lds[t] = c0 + c1 + c2 + c3;
    __syncthreads();
    for (int s = 1; s < 1024; s <<= 1) {
        int v = 0;
        if (t >= s) v = lds[t - s];
        __syncthreads();
        lds[t] += v;
        __syncthreads();
    }
    int excl = (t == 0) ? 0 : lds[t - 1];
    int ob = b * (N + 1) + t * 4;
    offs[ob + 0] = excl;
    offs[ob + 1] = excl + c0;
    offs[ob + 2] = excl + c0 + c1;
    offs[ob + 3] = excl + c0 + c1 + c2;
    if (t == 1023) offs[b * (N + 1) + N] = lds[1023];
    dinv[base + 0] = rsqrtf((float)(c0 + 1));
    dinv[base + 1] = rsqrtf((float)(c1 + 1));
    dinv[base + 2] = rsqrtf((float)(c2 + 1));
    dinv[base + 3] = rsqrtf((float)(c3 + 1));
}

// ---------------------------------------------------------------------------
// K3: scatter edge sources into CSR slots
__global__ __launch_bounds__(256) void fill_kernel(const int* __restrict__ ei,
                                                   const int* __restrict__ offs,
                                                   int* __restrict__ cursor,
                                                   int* __restrict__ csr) {
    int idx = blockIdx.x * 256 + threadIdx.x;
    int b = idx >> 17;
    int e = idx & (E - 1);
    int src = ei[(size_t)b * 2 * E + e];
    int dst = ei[(size_t)b * 2 * E + E + e];
    int pos = atomicAdd(&cursor[b * N + dst], 1);
    csr[(size_t)b * E + offs[b * (N + 1) + dst] + pos] = src;
}

// ---------------------------------------------------------------------------
// K4: aggregation out[b,v,:] = sum_{u->v} dinv[u]dinv[v] in[b,u,:] + dinv[v]^2 in[b,v,:]
// One wave (64 lanes) per node; lane handles 4 channels (float4, 16 B/lane).
__global__ __launch_bounds__(256) void agg_kernel(const float* __restrict__ in,
                                                  float* __restrict__ out,
                                                  const int* __restrict__ csr,
                                                  const int* __restrict__ offs,
                                                  const float* __restrict__ dinv) {
    int b = blockIdx.y;
    int v = blockIdx.x * 4 + (threadIdx.x >> 6);
    int lane = threadIdx.x & 63;
    const float* inb = in + (size_t)b * N * C;
    const int* cs = csr + (size_t)b * E;
    const float* dv_b = dinv + b * N;

    float dv = dv_b[v];
    int s = offs[b * (N + 1) + v];
    int e = offs[b * (N + 1) + v + 1];

    float4 xv = *(const float4*)(inb + (size_t)v * C + lane * 4);
    float sn = dv * dv;  // self-loop norm = 1/deg
    float4 acc;
    acc.x = sn * xv.x; acc.y = sn * xv.y; acc.z = sn * xv.z; acc.w = sn * xv.w;

    for (int i = s; i < e; ++i) {
        int u = cs[i];
        float nrm = dv * dv_b[u];
        float4 f = *(const float4*)(inb + (size_t)u * C + lane * 4);
        acc.x += nrm * f.x;
        acc.y += nrm * f.y;
        acc.z += nrm * f.z;
        acc.w += nrm * f.w;
    }
    *(float4*)(out + ((size_t)b * N + v) * C + lane * 4) = acc;
}

// ---------------------------------------------------------------------------
// K5: C[M,256] = A[M,256] @ W[256,256] + bias (+ optional ReLU).  f32 VALU GEMM.
// 64x64 tile per block (256 threads), BK=64, 4x4 micro-tile per thread.
template <bool RELU>
__global__ __launch_bounds__(256) void gemm_bias(const float* __restrict__ A,
                                                 const float* __restrict__ W,
                                                 const float* __restrict__ bias,
                                                 float* __restrict__ Cout) {
    constexpr int K = 256, NW = 256, BM = 64, BN = 64, BK = 64;
    __shared__ float As[BK][BM + 4];  // transposed: As[k][m]; stride 68 (x4B = 16B-aligned rows)
    __shared__ float Bs[BK][BN];

    int tid = threadIdx.x;
    int bn = blockIdx.x * BN;
    int bm = blockIdx.y * BM;
    int tx = tid & 15, ty = tid >> 4;

    float acc[4][4] = {};

    for (int k0 = 0; k0 < K; k0 += BK) {
        // A tile: 64 rows x 64 k = 1024 float4; 4 per thread
#pragma unroll
        for (int i = 0; i < 4; ++i) {
            int f = tid + i * 256;
            int row = f >> 4;            // 16 float4 per row
            int kf = (f & 15) << 2;
            float4 v = *(const float4*)(A + (size_t)(bm + row) * K + k0 + kf);
            As[kf + 0][row] = v.x;
            As[kf + 1][row] = v.y;
            As[kf + 2][row] = v.z;
            As[kf + 3][row] = v.w;
        }
        // B tile: 64 k-rows x 64 n = 1024 float4; 4 per thread
#pragma unroll
        for (int i = 0; i < 4; ++i) {
            int f = tid + i * 256;
            int kr = f >> 4;
            int nf = (f & 15) << 2;
            *(float4*)(&Bs[kr][nf]) = *(const float4*)(W + (size_t)(k0 + kr) * NW + bn + nf);
        }
        __syncthreads();
#pragma unroll
        for (int k = 0; k < BK; ++k) {
            float4 a = *(const float4*)(&As[k][ty << 2]);
            float4 bv = *(const float4*)(&Bs[k][tx << 2]);
            float av[4] = {a.x, a.y, a.z, a.w};
            float bb[4] = {bv.x, bv.y, bv.z, bv.w};
#pragma unroll
            for (int i = 0; i < 4; ++i)
#pragma unroll
                for (int j = 0; j < 4; ++j) acc[i][j] += av[i] * bb[j];
        }
        __syncthreads();
    }

    float4 bvec = *(const float4*)(bias + bn + (tx << 2));
    float bb[4] = {bvec.x, bvec.y, bvec.z, bvec.w};
#pragma unroll
    for (int i = 0; i < 4; ++i) {
        float4 o;
        float v0 = acc[i][0] + bb[0];
        float v1 = acc[i][1] + bb[1];
        float v2 = acc[i][2] + bb[2];
        float v3 = acc[i][3] + bb[3];
        if (RELU) {
            v0 = fmaxf(v0, 0.f); v1 = fmaxf(v1, 0.f);
            v2 = fmaxf(v2, 0.f); v3 = fmaxf(v3, 0.f);
        }
        o.x = v0; o.y = v1; o.z = v2; o.w = v3;
        *(float4*)(Cout + (size_t)(bm + ty * 4 + i) * NW + bn + (tx << 2)) = o;
    }
}

// ---------------------------------------------------------------------------
extern "C" void kernel_launch(void* const* d_in, const int* in_sizes, int n_in,
                              void* d_out, int out_size, void* d_ws, size_t ws_size,
                              hipStream_t stream) {
    const float* x  = (const float*)d_in[0];
    const int*   ei = (const int*)d_in[1];
    const float* W1 = (const float*)d_in[2];
    const float* b1 = (const float*)d_in[3];
    const float* W2 = (const float*)d_in[4];
    const float* b2 = (const float*)d_in[5];
    float* out = (float*)d_out;

    char* w = (char*)d_ws;
    float* dinv   = (float*)(w + 0x0);          // 128 KB (B*N floats)
    int*   counts = (int*)  (w + 0x20000);      // 128 KB
    int*   cursor = (int*)  (w + 0x40000);      // 128 KB
    int*   offs   = (int*)  (w + 0x60000);      // B*(N+1) ints ~128 KB (slot 192 KB)
    int*   csr    = (int*)  (w + 0x90000);      // 4 MB
    float* bufA   = (float*)(w + 0x500000);     // 32 MB
    float* bufB   = (float*)(w + 0x2500000);    // 32 MB -> total 0x4500000 (~69.3 MB)

    hipMemsetAsync(counts, 0, BN_TOT * sizeof(int), stream);
    hipMemsetAsync(cursor, 0, BN_TOT * sizeof(int), stream);

    count_kernel<<<(B * E) / 256, 256, 0, stream>>>(ei, counts);
    scan_kernel<<<B, 1024, 0, stream>>>(counts, offs, dinv);
    fill_kernel<<<(B * E) / 256, 256, 0, stream>>>(ei, offs, cursor, csr);

    dim3 agg_grid(N / 4, B);
    dim3 gemm_grid(C / 64, BN_TOT / 64);

    // layer 1: agg(x) -> bufA ; relu(bufA@W1+b1) -> bufB
    agg_kernel<<<agg_grid, 256, 0, stream>>>(x, bufA, csr, offs, dinv);
    gemm_bias<true><<<gemm_grid, 256, 0, stream>>>(bufA, W1, b1, bufB);
    // layer 2: agg(bufB) -> bufA ; bufA@W2+b2 -> out
    agg_kernel<<<agg_grid, 256, 0, stream>>>(bufB, bufA, csr, offs, dinv);
    gemm_bias<false><<<gemm_grid, 256, 0, stream>>>(bufA, W2, b2, out);
}

// Round 2
// 352.589 us; speedup vs baseline: 1.3037x; 1.3037x over previous
//
#include <hip/hip_runtime.h>

// Problem constants (from reference)
constexpr int B = 8;
constexpr int N = 4096;
constexpr int E = 131072;     // 2^17
constexpr int C = 256;
constexpr int BN_TOT = B * N; // 32768

// ---------------------------------------------------------------------------
// K1: count in-degree per (graph, node)
__global__ __launch_bounds__(256) void count_kernel(const int* __restrict__ ei,
                                                    int* __restrict__ counts) {
    int idx = blockIdx.x * 256 + threadIdx.x;   // [0, B*E)
    int b = idx >> 17;                          // / E
    int e = idx & (E - 1);
    int dst = ei[(size_t)b * 2 * E + E + e];
    atomicAdd(&counts[b * N + dst], 1);
}

// ---------------------------------------------------------------------------
// K2: per-graph exclusive scan of counts -> CSR offsets; also dinv = rsqrt(deg)
__global__ __launch_bounds__(1024) void scan_kernel(const int* __restrict__ counts,
                                                    int* __restrict__ offs,
                                                    float* __restrict__ dinv) {
    __shared__ int lds[1024];
    int b = blockIdx.x, t = threadIdx.x;
    int base = b * N + t * 4;
    int c0 = counts[base + 0];
    int c1 = counts[base + 1];
    int c2 = counts[base + 2];
    int c3 = counts[base + 3];
    lds[t] = c0 + c1 + c2 + c3;
    __syncthreads();
    for (int s = 1; s < 1024; s <<= 1) {
        int v = 0;
        if (t >= s) v = lds[t - s];
        __syncthreads();
        lds[t] += v;
        __syncthreads();
    }
    int excl = (t == 0) ? 0 : lds[t - 1];
    int ob = b * (N + 1) + t * 4;
    offs[ob + 0] = excl;
    offs[ob + 1] = excl + c0;
    offs[ob + 2] = excl + c0 + c1;
    offs[ob + 3] = excl + c0 + c1 + c2;
    if (t == 1023) offs[b * (N + 1) + N] = lds[1023];
    dinv[base + 0] = rsqrtf((float)(c0 + 1));
    dinv[base + 1] = rsqrtf((float)(c1 + 1));
    dinv[base + 2] = rsqrtf((float)(c2 + 1));
    dinv[base + 3] = rsqrtf((float)(c3 + 1));
}

// ---------------------------------------------------------------------------
// K3: scatter edge sources into CSR slots
__global__ __launch_bounds__(256) void fill_kernel(const int* __restrict__ ei,
                                                   const int* __restrict__ offs,
                                                   int* __restrict__ cursor,
                                                   int* __restrict__ csr) {
    int idx = blockIdx.x * 256 + threadIdx.x;
    int b = idx >> 17;
    int e = idx & (E - 1);
    int src = ei[(size_t)b * 2 * E + e];
    int dst = ei[(size_t)b * 2 * E + E + e];
    int pos = atomicAdd(&cursor[b * N + dst], 1);
    csr[(size_t)b * E + offs[b * (N + 1) + dst] + pos] = src;
}

// ---------------------------------------------------------------------------
// K4: aggregation out[b,v,:] = sum_{u->v} dinv[u]dinv[v] in[b,u,:] + dinv[v]^2 in[b,v,:]
// One wave (64 lanes) per node; lane handles 4 channels (float4, 16 B/lane).
// XCD-pinned: 1D grid, graph = blockIdx.x & 7 -> all of a graph's blocks land
// on one XCD (dispatch round-robin), so its 4 MB feature matrix stays L2-resident.
// 4-edge unroll: 4 outstanding gathers per wave to hide L2/HBM latency.
__global__ __launch_bounds__(256) void agg_kernel(const float* __restrict__ in,
                                                  float* __restrict__ out,
                                                  const int* __restrict__ csr,
                                                  const int* __restrict__ offs,
                                                  const float* __restrict__ dinv) {
    int bid = blockIdx.x;
    int b = bid & 7;
    int v = (bid >> 3) * 4 + (threadIdx.x >> 6);
    int lane = threadIdx.x & 63;
    const float* inb = in + (size_t)b * N * C;
    const int* cs = csr + (size_t)b * E;
    const float* dv_b = dinv + b * N;

    float dv = dv_b[v];
    int s = offs[b * (N + 1) + v];
    int e = offs[b * (N + 1) + v + 1];

    float4 xv = *(const float4*)(inb + (size_t)v * C + lane * 4);
    float sn = dv * dv;  // self-loop norm = 1/deg
    float4 acc;
    acc.x = sn * xv.x; acc.y = sn * xv.y; acc.z = sn * xv.z; acc.w = sn * xv.w;

    int i = s;
    for (; i + 4 <= e; i += 4) {
        int u0 = cs[i + 0];
        int u1 = cs[i + 1];
        int u2 = cs[i + 2];
        int u3 = cs[i + 3];
        float n0 = dv * dv_b[u0];
        float n1 = dv * dv_b[u1];
        float n2 = dv * dv_b[u2];
        float n3 = dv * dv_b[u3];
        float4 f0 = *(const float4*)(inb + (size_t)u0 * C + lane * 4);
        float4 f1 = *(const float4*)(inb + (size_t)u1 * C + lane * 4);
        float4 f2 = *(const float4*)(inb + (size_t)u2 * C + lane * 4);
        float4 f3 = *(const float4*)(inb + (size_t)u3 * C + lane * 4);
        acc.x += n0 * f0.x; acc.y += n0 * f0.y; acc.z += n0 * f0.z; acc.w += n0 * f0.w;
        acc.x += n1 * f1.x; acc.y += n1 * f1.y; acc.z += n1 * f1.z; acc.w += n1 * f1.w;
        acc.x += n2 * f2.x; acc.y += n2 * f2.y; acc.z += n2 * f2.z; acc.w += n2 * f2.w;
        acc.x += n3 * f3.x; acc.y += n3 * f3.y; acc.z += n3 * f3.z; acc.w += n3 * f3.w;
    }
    for (; i < e; ++i) {
        int u = cs[i];
        float nrm = dv * dv_b[u];
        float4 f = *(const float4*)(inb + (size_t)u * C + lane * 4);
        acc.x += nrm * f.x;
        acc.y += nrm * f.y;
        acc.z += nrm * f.z;
        acc.w += nrm * f.w;
    }
    *(float4*)(out + ((size_t)b * N + v) * C + lane * 4) = acc;
}

// ---------------------------------------------------------------------------
// K5: C[M,256] = A[M,256] @ W[256,256] + bias (+ optional ReLU).  f32 VALU GEMM.
// 64x64 tile per block (256 threads), BK=64, 4x4 micro-tile per thread.
template <bool RELU>
__global__ __launch_bounds__(256) void gemm_bias(const float* __restrict__ A,
                                                 const float* __restrict__ W,
                                                 const float* __restrict__ bias,
                                                 float* __restrict__ Cout) {
    constexpr int K = 256, NW = 256, BM = 64, BN = 64, BK = 64;
    __shared__ float As[BK][BM + 4];  // transposed: As[k][m]; stride 68 (x4B = 16B-aligned rows)
    __shared__ float Bs[BK][BN];

    int tid = threadIdx.x;
    int bn = blockIdx.x * BN;
    int bm = blockIdx.y * BM;
    int tx = tid & 15, ty = tid >> 4;

    float acc[4][4] = {};

    for (int k0 = 0; k0 < K; k0 += BK) {
        // A tile: 64 rows x 64 k = 1024 float4; 4 per thread
#pragma unroll
        for (int i = 0; i < 4; ++i) {
            int f = tid + i * 256;
            int row = f >> 4;            // 16 float4 per row
            int kf = (f & 15) << 2;
            float4 v = *(const float4*)(A + (size_t)(bm + row) * K + k0 + kf);
            As[kf + 0][row] = v.x;
            As[kf + 1][row] = v.y;
            As[kf + 2][row] = v.z;
            As[kf + 3][row] = v.w;
        }
        // B tile: 64 k-rows x 64 n = 1024 float4; 4 per thread
#pragma unroll
        for (int i = 0; i < 4; ++i) {
            int f = tid + i * 256;
            int kr = f >> 4;
            int nf = (f & 15) << 2;
            *(float4*)(&Bs[kr][nf]) = *(const float4*)(W + (size_t)(k0 + kr) * NW + bn + nf);
        }
        __syncthreads();
#pragma unroll
        for (int k = 0; k < BK; ++k) {
            float4 a = *(const float4*)(&As[k][ty << 2]);
            float4 bv = *(const float4*)(&Bs[k][tx << 2]);
            float av[4] = {a.x, a.y, a.z, a.w};
            float bb[4] = {bv.x, bv.y, bv.z, bv.w};
#pragma unroll
            for (int i = 0; i < 4; ++i)
#pragma unroll
                for (int j = 0; j < 4; ++j) acc[i][j] += av[i] * bb[j];
        }
        __syncthreads();
    }

    float4 bvec = *(const float4*)(bias + bn + (tx << 2));
    float bb[4] = {bvec.x, bvec.y, bvec.z, bvec.w};
#pragma unroll
    for (int i = 0; i < 4; ++i) {
        float4 o;
        float v0 = acc[i][0] + bb[0];
        float v1 = acc[i][1] + bb[1];
        float v2 = acc[i][2] + bb[2];
        float v3 = acc[i][3] + bb[3];
        if (RELU) {
            v0 = fmaxf(v0, 0.f); v1 = fmaxf(v1, 0.f);
            v2 = fmaxf(v2, 0.f); v3 = fmaxf(v3, 0.f);
        }
        o.x = v0; o.y = v1; o.z = v2; o.w = v3;
        *(float4*)(Cout + (size_t)(bm + ty * 4 + i) * NW + bn + (tx << 2)) = o;
    }
}

// ---------------------------------------------------------------------------
extern "C" void kernel_launch(void* const* d_in, const int* in_sizes, int n_in,
                              void* d_out, int out_size, void* d_ws, size_t ws_size,
                              hipStream_t stream) {
    const float* x  = (const float*)d_in[0];
    const int*   ei = (const int*)d_in[1];
    const float* W1 = (const float*)d_in[2];
    const float* b1 = (const float*)d_in[3];
    const float* W2 = (const float*)d_in[4];
    const float* b2 = (const float*)d_in[5];
    float* out = (float*)d_out;

    char* w = (char*)d_ws;
    float* dinv   = (float*)(w + 0x0);          // 128 KB (B*N floats)
    int*   counts = (int*)  (w + 0x20000);      // 128 KB
    int*   cursor = (int*)  (w + 0x40000);      // 128 KB
    int*   offs   = (int*)  (w + 0x60000);      // B*(N+1) ints ~128 KB (slot 192 KB)
    int*   csr    = (int*)  (w + 0x90000);      // 4 MB
    float* bufA   = (float*)(w + 0x500000);     // 32 MB
    float* bufB   = (float*)(w + 0x2500000);    // 32 MB -> total 0x4500000 (~69.3 MB)

    hipMemsetAsync(counts, 0, BN_TOT * sizeof(int), stream);
    hipMemsetAsync(cursor, 0, BN_TOT * sizeof(int), stream);

    count_kernel<<<(B * E) / 256, 256, 0, stream>>>(ei, counts);
    scan_kernel<<<B, 1024, 0, stream>>>(counts, offs, dinv);
    fill_kernel<<<(B * E) / 256, 256, 0, stream>>>(ei, offs, cursor, csr);

    dim3 agg_grid(B * N / 4);   // 1D: graph = bid & 7 (XCD-pinned)
    dim3 gemm_grid(C / 64, BN_TOT / 64);

    // layer 1: agg(x) -> bufA ; relu(bufA@W1+b1) -> bufB
    agg_kernel<<<agg_grid, 256, 0, stream>>>(x, bufA, csr, offs, dinv);
    gemm_bias<true><<<gemm_grid, 256, 0, stream>>>(bufA, W1, b1, bufB);
    // layer 2: agg(bufB) -> bufA ; bufA@W2+b2 -> out
    agg_kernel<<<agg_grid, 256, 0, stream>>>(bufB, bufA, csr, offs, dinv);
    gemm_bias<false><<<gemm_grid, 256, 0, stream>>>(bufA, W2, b2, out);
}

// Round 3
// 247.653 us; speedup vs baseline: 1.8562x; 1.4237x over previous
//
#include <hip/hip_runtime.h>

// Problem constants (from reference)
constexpr int B = 8;
constexpr int N = 4096;
constexpr int E = 131072;     // 2^17
constexpr int C = 256;
constexpr int BN_TOT = B * N; // 32768

typedef __attribute__((ext_vector_type(8))) short s16x8;
typedef __attribute__((ext_vector_type(4))) float f32x4;

__device__ __forceinline__ unsigned short f2bf(float f) {
    unsigned u = __float_as_uint(f);
    unsigned r = (u + 0x7FFFu + ((u >> 16) & 1u)) >> 16;   // RNE
    return (unsigned short)r;
}
__device__ __forceinline__ float b2f(unsigned short u) {
    return __uint_as_float(((unsigned)u) << 16);
}

// ---------------------------------------------------------------------------
// K1: count in-degree per (graph, node)
__global__ __launch_bounds__(256) void count_kernel(const int* __restrict__ ei,
                                                    int* __restrict__ counts) {
    int idx = blockIdx.x * 256 + threadIdx.x;   // [0, B*E)
    int b = idx >> 17;
    int e = idx & (E - 1);
    int dst = ei[(size_t)b * 2 * E + E + e];
    atomicAdd(&counts[b * N + dst], 1);
}

// ---------------------------------------------------------------------------
// K2: per-graph exclusive scan of counts -> CSR offsets; dinv = rsqrt(deg+1)
__global__ __launch_bounds__(1024) void scan_kernel(const int* __restrict__ counts,
                                                    int* __restrict__ offs,
                                                    float* __restrict__ dinv) {
    __shared__ int lds[1024];
    int b = blockIdx.x, t = threadIdx.x;
    int base = b * N + t * 4;
    int c0 = counts[base + 0];
    int c1 = counts[base + 1];
    int c2 = counts[base + 2];
    int c3 = counts[base + 3];
    lds[t] = c0 + c1 + c2 + c3;
    __syncthreads();
    for (int s = 1; s < 1024; s <<= 1) {
        int v = 0;
        if (t >= s) v = lds[t - s];
        __syncthreads();
        lds[t] += v;
        __syncthreads();
    }
    int excl = (t == 0) ? 0 : lds[t - 1];
    int ob = b * (N + 1) + t * 4;
    offs[ob + 0] = excl;
    offs[ob + 1] = excl + c0;
    offs[ob + 2] = excl + c0 + c1;
    offs[ob + 3] = excl + c0 + c1 + c2;
    if (t == 1023) offs[b * (N + 1) + N] = lds[1023];
    dinv[base + 0] = rsqrtf((float)(c0 + 1));
    dinv[base + 1] = rsqrtf((float)(c1 + 1));
    dinv[base + 2] = rsqrtf((float)(c2 + 1));
    dinv[base + 3] = rsqrtf((float)(c3 + 1));
}

// ---------------------------------------------------------------------------
// K3: scatter edge sources into CSR slots
__global__ __launch_bounds__(256) void fill_kernel(const int* __restrict__ ei,
                                                   const int* __restrict__ offs,
                                                   int* __restrict__ cursor,
                                                   int* __restrict__ csr) {
    int idx = blockIdx.x * 256 + threadIdx.x;
    int b = idx >> 17;
    int e = idx & (E - 1);
    int src = ei[(size_t)b * 2 * E + e];
    int dst = ei[(size_t)b * 2 * E + E + e];
    int pos = atomicAdd(&cursor[b * N + dst], 1);
    csr[(size_t)b * E + offs[b * (N + 1) + dst] + pos] = src;
}

// ---------------------------------------------------------------------------
// K4: x (f32) -> xb (bf16), XCD-pinned per graph
__global__ __launch_bounds__(256) void xconv_kernel(const float* __restrict__ x,
                                                    unsigned short* __restrict__ xb) {
    int bid = blockIdx.x;
    int g = bid & 7;
    int off = bid >> 3;                          // [0,1024)
    size_t base = (size_t)g * (N * C) + (size_t)off * 1024 + threadIdx.x * 4;
    float4 v = *(const float4*)(x + base);
    ushort4 o;
    o.x = f2bf(v.x); o.y = f2bf(v.y); o.z = f2bf(v.z); o.w = f2bf(v.w);
    *(ushort4*)(xb + base) = o;
}

// ---------------------------------------------------------------------------
// K5: W [K][N] f32 -> Wt [N][K] bf16 (transposed)
__global__ __launch_bounds__(64) void prep_w(const float* __restrict__ W1,
                                             const float* __restrict__ W2,
                                             unsigned short* __restrict__ Wt1,
                                             unsigned short* __restrict__ Wt2) {
    int n = blockIdx.x & 255;
    int w = blockIdx.x >> 8;
    const float* W = w ? W2 : W1;
    unsigned short* Wt = w ? Wt2 : Wt1;
#pragma unroll
    for (int i = 0; i < 4; ++i) {
        int k = threadIdx.x + i * 64;
        Wt[n * 256 + k] = f2bf(W[k * 256 + n]);
    }
}

// ---------------------------------------------------------------------------
// K6: aggregation over bf16 features. One wave per node, 4 bf16/lane (8 B).
// out[b,v,:] = sum_{u->v} dinv[u]dinv[v] in[b,u,:] + dinv[v]^2 in[b,v,:]
__global__ __launch_bounds__(256) void agg_bf16(const unsigned short* __restrict__ in,
                                                unsigned short* __restrict__ out,
                                                const int* __restrict__ csr,
                                                const int* __restrict__ offs,
                                                const float* __restrict__ dinv) {
    int bid = blockIdx.x;
    int b = bid & 7;                      // XCD-pinned graph
    int v = (bid >> 3) * 4 + (threadIdx.x >> 6);
    int lane = threadIdx.x & 63;
    const unsigned short* inb = in + (size_t)b * (N * C);
    const int* cs = csr + (size_t)b * E;
    const float* dv_b = dinv + b * N;

    float dv = dv_b[v];
    int s = offs[b * (N + 1) + v];
    int e = offs[b * (N + 1) + v + 1];

    ushort4 xv = *(const ushort4*)(inb + (size_t)v * C + lane * 4);
    float sn = dv * dv;
    float4 acc;
    acc.x = sn * b2f(xv.x); acc.y = sn * b2f(xv.y);
    acc.z = sn * b2f(xv.z); acc.w = sn * b2f(xv.w);

    int i = s;
    for (; i + 4 <= e; i += 4) {
        int u0 = cs[i + 0];
        int u1 = cs[i + 1];
        int u2 = cs[i + 2];
        int u3 = cs[i + 3];
        float n0 = dv * dv_b[u0];
        float n1 = dv * dv_b[u1];
        float n2 = dv * dv_b[u2];
        float n3 = dv * dv_b[u3];
        ushort4 f0 = *(const ushort4*)(inb + (size_t)u0 * C + lane * 4);
        ushort4 f1 = *(const ushort4*)(inb + (size_t)u1 * C + lane * 4);
        ushort4 f2 = *(const ushort4*)(inb + (size_t)u2 * C + lane * 4);
        ushort4 f3 = *(const ushort4*)(inb + (size_t)u3 * C + lane * 4);
        acc.x += n0 * b2f(f0.x); acc.y += n0 * b2f(f0.y); acc.z += n0 * b2f(f0.z); acc.w += n0 * b2f(f0.w);
        acc.x += n1 * b2f(f1.x); acc.y += n1 * b2f(f1.y); acc.z += n1 * b2f(f1.z); acc.w += n1 * b2f(f1.w);
        acc.x += n2 * b2f(f2.x); acc.y += n2 * b2f(f2.y); acc.z += n2 * b2f(f2.z); acc.w += n2 * b2f(f2.w);
        acc.x += n3 * b2f(f3.x); acc.y += n3 * b2f(f3.y); acc.z += n3 * b2f(f3.z); acc.w += n3 * b2f(f3.w);
    }
    for (; i < e; ++i) {
        int u = cs[i];
        float nrm = dv * dv_b[u];
        ushort4 f = *(const ushort4*)(inb + (size_t)u * C + lane * 4);
        acc.x += nrm * b2f(f.x); acc.y += nrm * b2f(f.y);
        acc.z += nrm * b2f(f.z); acc.w += nrm * b2f(f.w);
    }
    ushort4 o;
    o.x = f2bf(acc.x); o.y = f2bf(acc.y); o.z = f2bf(acc.z); o.w = f2bf(acc.w);
    *(ushort4*)(out + ((size_t)b * N + v) * C + lane * 4) = o;
}

// ---------------------------------------------------------------------------
// K7: bf16 MFMA GEMM: Cout[M,256] = A[M,256] @ W[256,256] (+bias, opt ReLU).
// A bf16 row-major; Wt bf16 TRANSPOSED [N][K]. Block: 256 thr = 4 waves,
// tile 128x64, K-chunks of 64. LDS: Ws slice [64][256] (32KB, staged once) +
// As chunk [128][64] (16KB), both XOR-swizzled (byte ^= (row&7)<<4).
// A/B fragments use the same (lane-group, slot)->k bijection, so the MFMA
// pairs them consistently regardless of the HW's internal k naming.
// C/D layout (HW-verified): col = lane&15, row = (lane>>4)*4 + reg.
template <bool RELU, bool BF16OUT>
__global__ __launch_bounds__(256) void gemm_mfma(const unsigned short* __restrict__ A,
                                                 const unsigned short* __restrict__ Wt,
                                                 const float* __restrict__ bias,
                                                 void* __restrict__ Cout) {
    __shared__ __align__(16) char lds[49152];
    char* WsB = lds;            // 32 KB: [64 n][256 k] bf16, swizzled
    char* AsB = lds + 32768;    // 16 KB: [128 m][64 k] bf16, swizzled

    int tid = threadIdx.x;
    int bid = blockIdx.x;
    int g = bid & 7;                 // XCD-pinned graph
    int i = bid >> 3;                // [0,128)
    int mloc = i >> 2;               // [0,32)
    int nb = i & 3;                  // [0,4)
    int bm = g * 4096 + mloc * 128;
    int bn = nb * 64;

    // Stage W-slice: Wt rows [bn, bn+64), all 256 k. 2048 x 16B chunks.
#pragma unroll
    for (int c = 0; c < 8; ++c) {
        int f = tid + c * 256;
        int n = f >> 5;              // [0,64)
        int slot = f & 31;           // 16B slot within 512B row
        s16x8 v = *(const s16x8*)(Wt + (size_t)(bn + n) * 256 + slot * 8);
        *(s16x8*)(WsB + n * 512 + ((slot * 16) ^ ((n & 7) << 4))) = v;
    }

    const int l = tid & 63;
    const int w = tid >> 6;
    const int lr = l & 15;
    const int lg = l >> 4;

    f32x4 acc[2][4] = {};

    for (int kc = 0; kc < 4; ++kc) {
        __syncthreads();             // protect As from prior-iter readers
        // Stage A chunk: [128 rows][64 k] = 1024 x 16B chunks.
#pragma unroll
        for (int c = 0; c < 4; ++c) {
            int f = tid + c * 256;
            int row = f >> 3;
            int slot = f & 7;
            s16x8 v = *(const s16x8*)(A + (size_t)(bm + row) * 256 + kc * 64 + slot * 8);
            *(s16x8*)(AsB + row * 128 + ((slot * 16) ^ ((row & 7) << 4))) = v;
        }
        __syncthreads();

#pragma unroll
        for (int ks = 0; ks < 2; ++ks) {
            // A fragments: row = w*32 + m*16 + lr, k-slot = ks*32 + lg*8
            s16x8 af[2];
#pragma unroll
            for (int m = 0; m < 2; ++m) {
                int row = w * 32 + m * 16 + lr;
                int bir = ks * 64 + lg * 16;          // byte within 128B row
                af[m] = *(const s16x8*)(AsB + row * 128 + (bir ^ ((row & 7) << 4)));
            }
            // W fragments: col = n*16 + lr, k = kc*64 + ks*32 + lg*8
            s16x8 wf[4];
#pragma unroll
            for (int n = 0; n < 4; ++n) {
                int cidx = n * 16 + lr;
                int bir = (kc * 64 + ks * 32 + lg * 8) * 2; // byte within 512B row
                wf[n] = *(const s16x8*)(WsB + cidx * 512 + (bir ^ ((cidx & 7) << 4)));
            }
#pragma unroll
            for (int m = 0; m < 2; ++m)
#pragma unroll
                for (int n = 0; n < 4; ++n)
                    acc[m][n] = __builtin_amdgcn_mfma_f32_16x16x32_bf16(af[m], wf[n], acc[m][n], 0, 0, 0);
        }
    }

    // Epilogue: D col = lane&15, row = (lane>>4)*4 + reg
#pragma unroll
    for (int m = 0; m < 2; ++m) {
#pragma unroll
        for (int n = 0; n < 4; ++n) {
            int col = bn + n * 16 + lr;
            float bb = bias[col];
            int base_row = bm + w * 32 + m * 16 + lg * 4;
            f32x4 v = acc[m][n];
#pragma unroll
            for (int r = 0; r < 4; ++r) {
                float o = v[r] + bb;
                if (RELU) o = fmaxf(o, 0.f);
                if (BF16OUT)
                    ((unsigned short*)Cout)[(size_t)(base_row + r) * 256 + col] = f2bf(o);
                else
                    ((float*)Cout)[(size_t)(base_row + r) * 256 + col] = o;
            }
        }
    }
}

// ---------------------------------------------------------------------------
extern "C" void kernel_launch(void* const* d_in, const int* in_sizes, int n_in,
                              void* d_out, int out_size, void* d_ws, size_t ws_size,
                              hipStream_t stream) {
    const float* x  = (const float*)d_in[0];
    const int*   ei = (const int*)d_in[1];
    const float* W1 = (const float*)d_in[2];
    const float* b1 = (const float*)d_in[3];
    const float* W2 = (const float*)d_in[4];
    const float* b2 = (const float*)d_in[5];
    float* out = (float*)d_out;

    char* w = (char*)d_ws;
    float* dinv            = (float*)(w + 0x0);        // 128 KB
    int*   counts          = (int*)  (w + 0x20000);    // 128 KB
    int*   cursor          = (int*)  (w + 0x40000);    // 128 KB
    int*   offs            = (int*)  (w + 0x60000);    // ~128 KB
    int*   csr             = (int*)  (w + 0x90000);    // 4 MB
    unsigned short* Wt1    = (unsigned short*)(w + 0x4A0000);   // 128 KB
    unsigned short* Wt2    = (unsigned short*)(w + 0x4C0000);   // 128 KB
    unsigned short* xb     = (unsigned short*)(w + 0x500000);   // 16 MB
    unsigned short* bufA   = (unsigned short*)(w + 0x1500000);  // 16 MB
    unsigned short* bufB   = (unsigned short*)(w + 0x2500000);  // 16 MB
    unsigned short* bufC   = (unsigned short*)(w + 0x3500000);  // 16 MB (ends 0x4500000)

    hipMemsetAsync(counts, 0, BN_TOT * sizeof(int), stream);
    hipMemsetAsync(cursor, 0, BN_TOT * sizeof(int), stream);

    count_kernel<<<(B * E) / 256, 256, 0, stream>>>(ei, counts);
    scan_kernel<<<B, 1024, 0, stream>>>(counts, offs, dinv);
    fill_kernel<<<(B * E) / 256, 256, 0, stream>>>(ei, offs, cursor, csr);
    prep_w<<<512, 64, 0, stream>>>(W1, W2, Wt1, Wt2);
    xconv_kernel<<<8192, 256, 0, stream>>>(x, xb);

    // layer 1
    agg_bf16<<<8192, 256, 0, stream>>>(xb, bufA, csr, offs, dinv);
    gemm_mfma<true, true><<<1024, 256, 0, stream>>>(bufA, Wt1, b1, bufB);
    // layer 2
    agg_bf16<<<8192, 256, 0, stream>>>(bufB, bufC, csr, offs, dinv);
    gemm_mfma<false, false><<<1024, 256, 0, stream>>>(bufC, Wt2, b2, out);
}

// Round 4
// 234.919 us; speedup vs baseline: 1.9568x; 1.0542x over previous
//
#include <hip/hip_runtime.h>

// Problem constants (from reference)
constexpr int B = 8;
constexpr int N = 4096;
constexpr int E = 131072;     // 2^17
constexpr int C = 256;
constexpr int BN_TOT = B * N; // 32768

typedef __attribute__((ext_vector_type(8))) short s16x8;
typedef __attribute__((ext_vector_type(4))) float f32x4;

__device__ __forceinline__ unsigned short f2bf(float f) {
    unsigned u = __float_as_uint(f);
    unsigned r = (u + 0x7FFFu + ((u >> 16) & 1u)) >> 16;   // RNE
    return (unsigned short)r;
}
__device__ __forceinline__ float b2f(unsigned short u) {
    return __uint_as_float(((unsigned)u) << 16);
}

// ---------------------------------------------------------------------------
// K1: count in-degree per (graph, node)
__global__ __launch_bounds__(256) void count_kernel(const int* __restrict__ ei,
                                                    int* __restrict__ counts) {
    int idx = blockIdx.x * 256 + threadIdx.x;   // [0, B*E)
    int b = idx >> 17;
    int e = idx & (E - 1);
    int dst = ei[(size_t)b * 2 * E + E + e];
    atomicAdd(&counts[b * N + dst], 1);
}

// ---------------------------------------------------------------------------
// K2: per-graph exclusive scan of counts -> CSR offsets; dinv = rsqrt(deg+1)
__global__ __launch_bounds__(1024) void scan_kernel(const int* __restrict__ counts,
                                                    int* __restrict__ offs,
                                                    float* __restrict__ dinv) {
    __shared__ int lds[1024];
    int b = blockIdx.x, t = threadIdx.x;
    int base = b * N + t * 4;
    int c0 = counts[base + 0];
    int c1 = counts[base + 1];
    int c2 = counts[base + 2];
    int c3 = counts[base + 3];
    lds[t] = c0 + c1 + c2 + c3;
    __syncthreads();
    for (int s = 1; s < 1024; s <<= 1) {
        int v = 0;
        if (t >= s) v = lds[t - s];
        __syncthreads();
        lds[t] += v;
        __syncthreads();
    }
    int excl = (t == 0) ? 0 : lds[t - 1];
    int ob = b * (N + 1) + t * 4;
    offs[ob + 0] = excl;
    offs[ob + 1] = excl + c0;
    offs[ob + 2] = excl + c0 + c1;
    offs[ob + 3] = excl + c0 + c1 + c2;
    if (t == 1023) offs[b * (N + 1) + N] = lds[1023];
    dinv[base + 0] = rsqrtf((float)(c0 + 1));
    dinv[base + 1] = rsqrtf((float)(c1 + 1));
    dinv[base + 2] = rsqrtf((float)(c2 + 1));
    dinv[base + 3] = rsqrtf((float)(c3 + 1));
}

// ---------------------------------------------------------------------------
// K3: scatter edge sources into CSR slots
__global__ __launch_bounds__(256) void fill_kernel(const int* __restrict__ ei,
                                                   const int* __restrict__ offs,
                                                   int* __restrict__ cursor,
                                                   int* __restrict__ csr) {
    int idx = blockIdx.x * 256 + threadIdx.x;
    int b = idx >> 17;
    int e = idx & (E - 1);
    int src = ei[(size_t)b * 2 * E + e];
    int dst = ei[(size_t)b * 2 * E + E + e];
    int pos = atomicAdd(&cursor[b * N + dst], 1);
    csr[(size_t)b * E + offs[b * (N + 1) + dst] + pos] = src;
}

// ---------------------------------------------------------------------------
// K4: y1 = dinv[row] * x (f32 -> bf16), XCD-pinned per graph
__global__ __launch_bounds__(256) void xconv_kernel(const float* __restrict__ x,
                                                    unsigned short* __restrict__ xb,
                                                    const float* __restrict__ dinv) {
    int bid = blockIdx.x;
    int g = bid & 7;
    int off = bid >> 3;                          // [0,1024)
    size_t base = (size_t)g * (N * C) + (size_t)off * 1024 + threadIdx.x * 4;
    float dv = dinv[g * N + off * 4 + (threadIdx.x >> 6)];
    float4 v = *(const float4*)(x + base);
    ushort4 o;
    o.x = f2bf(dv * v.x); o.y = f2bf(dv * v.y);
    o.z = f2bf(dv * v.z); o.w = f2bf(dv * v.w);
    *(ushort4*)(xb + base) = o;
}

// ---------------------------------------------------------------------------
// K5: W [K][N] f32 -> Wt [N][K] bf16 (transposed)
__global__ __launch_bounds__(64) void prep_w(const float* __restrict__ W1,
                                             const float* __restrict__ W2,
                                             unsigned short* __restrict__ Wt1,
                                             unsigned short* __restrict__ Wt2) {
    int n = blockIdx.x & 255;
    int w = blockIdx.x >> 8;
    const float* W = w ? W2 : W1;
    unsigned short* Wt = w ? Wt2 : Wt1;
#pragma unroll
    for (int i = 0; i < 4; ++i) {
        int k = threadIdx.x + i * 64;
        Wt[n * 256 + k] = f2bf(W[k * 256 + n]);
    }
}

// ---------------------------------------------------------------------------
// K6: norm-free aggregation over pre-scaled bf16 features y:
//   out[b,v,:] = dinv[v] * ( y[b,v,:] + sum_{u->v} y[b,u,:] )
// One wave per node; lane holds 4 channels (8 B). 8-deep software pipeline:
// 8 feature gathers + next 8 index loads in flight simultaneously.
__global__ __launch_bounds__(256) void agg_sum(const unsigned short* __restrict__ in,
                                               unsigned short* __restrict__ out,
                                               const int* __restrict__ csr,
                                               const int* __restrict__ offs,
                                               const float* __restrict__ dinv) {
    int bid = blockIdx.x;
    int b = bid & 7;                      // XCD-pinned graph
    int v = (bid >> 3) * 4 + (threadIdx.x >> 6);
    int lane = threadIdx.x & 63;
    const unsigned short* inb = in + (size_t)b * (N * C) + lane * 4;
    const int* cs = csr + (size_t)b * E;

    int s = offs[b * (N + 1) + v];
    int e = offs[b * (N + 1) + v + 1];

    ushort4 xv = *(const ushort4*)(inb + (size_t)v * C);
    float4 acc;
    acc.x = b2f(xv.x); acc.y = b2f(xv.y); acc.z = b2f(xv.z); acc.w = b2f(xv.w);

    int i = s;
    if (i + 8 <= e) {
        int u[8];
#pragma unroll
        for (int j = 0; j < 8; ++j) u[j] = cs[i + j];
        for (; i + 16 <= e; i += 8) {
            ushort4 f[8];
#pragma unroll
            for (int j = 0; j < 8; ++j) f[j] = *(const ushort4*)(inb + (size_t)u[j] * C);
#pragma unroll
            for (int j = 0; j < 8; ++j) u[j] = cs[i + 8 + j];
#pragma unroll
            for (int j = 0; j < 8; ++j) {
                acc.x += b2f(f[j].x); acc.y += b2f(f[j].y);
                acc.z += b2f(f[j].z); acc.w += b2f(f[j].w);
            }
        }
        {   // drain the last preloaded batch
            ushort4 f[8];
#pragma unroll
            for (int j = 0; j < 8; ++j) f[j] = *(const ushort4*)(inb + (size_t)u[j] * C);
#pragma unroll
            for (int j = 0; j < 8; ++j) {
                acc.x += b2f(f[j].x); acc.y += b2f(f[j].y);
                acc.z += b2f(f[j].z); acc.w += b2f(f[j].w);
            }
            i += 8;
        }
    }
    for (; i < e; ++i) {
        int uu = cs[i];
        ushort4 f = *(const ushort4*)(inb + (size_t)uu * C);
        acc.x += b2f(f.x); acc.y += b2f(f.y); acc.z += b2f(f.z); acc.w += b2f(f.w);
    }

    float dv = dinv[b * N + v];
    ushort4 o;
    o.x = f2bf(dv * acc.x); o.y = f2bf(dv * acc.y);
    o.z = f2bf(dv * acc.z); o.w = f2bf(dv * acc.w);
    *(ushort4*)(out + ((size_t)b * N + v) * C + lane * 4) = o;
}

// ---------------------------------------------------------------------------
// K7: bf16 MFMA GEMM: Cout[M,256] = A[M,256] @ W[256,256] (+bias, opt ReLU,
// opt row-scale by dinv for the next layer's pre-scaled y).
// A bf16 row-major; Wt bf16 TRANSPOSED [N][K]. 256 thr = 4 waves, tile 128x64,
// K-chunks of 64. LDS XOR-swizzled (byte ^= (row&7)<<4).
// C/D layout (HW-verified): col = lane&15, row = (lane>>4)*4 + reg.
template <bool RELU, bool BF16OUT, bool SCALE>
__global__ __launch_bounds__(256) void gemm_mfma(const unsigned short* __restrict__ A,
                                                 const unsigned short* __restrict__ Wt,
                                                 const float* __restrict__ bias,
                                                 const float* __restrict__ dinv,
                                                 void* __restrict__ Cout) {
    __shared__ __align__(16) char lds[49152];
    char* WsB = lds;            // 32 KB: [64 n][256 k] bf16, swizzled
    char* AsB = lds + 32768;    // 16 KB: [128 m][64 k] bf16, swizzled

    int tid = threadIdx.x;
    int bid = blockIdx.x;
    int g = bid & 7;                 // XCD-pinned graph
    int i = bid >> 3;                // [0,128)
    int mloc = i >> 2;               // [0,32)
    int nb = i & 3;                  // [0,4)
    int bm = g * 4096 + mloc * 128;
    int bn = nb * 64;

    // Stage W-slice: Wt rows [bn, bn+64), all 256 k. 2048 x 16B chunks.
#pragma unroll
    for (int c = 0; c < 8; ++c) {
        int f = tid + c * 256;
        int n = f >> 5;              // [0,64)
        int slot = f & 31;           // 16B slot within 512B row
        s16x8 v = *(const s16x8*)(Wt + (size_t)(bn + n) * 256 + slot * 8);
        *(s16x8*)(WsB + n * 512 + ((slot * 16) ^ ((n & 7) << 4))) = v;
    }

    const int l = tid & 63;
    const int w = tid >> 6;
    const int lr = l & 15;
    const int lg = l >> 4;

    f32x4 acc[2][4] = {};

    for (int kc = 0; kc < 4; ++kc) {
        __syncthreads();             // protect As from prior-iter readers
        // Stage A chunk: [128 rows][64 k] = 1024 x 16B chunks.
#pragma unroll
        for (int c = 0; c < 4; ++c) {
            int f = tid + c * 256;
            int row = f >> 3;
            int slot = f & 7;
            s16x8 v = *(const s16x8*)(A + (size_t)(bm + row) * 256 + kc * 64 + slot * 8);
            *(s16x8*)(AsB + row * 128 + ((slot * 16) ^ ((row & 7) << 4))) = v;
        }
        __syncthreads();

#pragma unroll
        for (int ks = 0; ks < 2; ++ks) {
            // A fragments: row = w*32 + m*16 + lr, k-slot = ks*32 + lg*8
            s16x8 af[2];
#pragma unroll
            for (int m = 0; m < 2; ++m) {
                int row = w * 32 + m * 16 + lr;
                int bir = ks * 64 + lg * 16;          // byte within 128B row
                af[m] = *(const s16x8*)(AsB + row * 128 + (bir ^ ((row & 7) << 4)));
            }
            // W fragments: col = n*16 + lr, k = kc*64 + ks*32 + lg*8
            s16x8 wf[4];
#pragma unroll
            for (int n = 0; n < 4; ++n) {
                int cidx = n * 16 + lr;
                int bir = (kc * 64 + ks * 32 + lg * 8) * 2; // byte within 512B row
                wf[n] = *(const s16x8*)(WsB + cidx * 512 + (bir ^ ((cidx & 7) << 4)));
            }
#pragma unroll
            for (int m = 0; m < 2; ++m)
#pragma unroll
                for (int n = 0; n < 4; ++n)
                    acc[m][n] = __builtin_amdgcn_mfma_f32_16x16x32_bf16(af[m], wf[n], acc[m][n], 0, 0, 0);
        }
    }

    // Epilogue: D col = lane&15, row = (lane>>4)*4 + reg
#pragma unroll
    for (int m = 0; m < 2; ++m) {
        int base_row = bm + w * 32 + m * 16 + lg * 4;
        float4 dv4 = make_float4(1.f, 1.f, 1.f, 1.f);
        if (SCALE) dv4 = *(const float4*)(dinv + base_row);
        float dvr[4] = {dv4.x, dv4.y, dv4.z, dv4.w};
#pragma unroll
        for (int n = 0; n < 4; ++n) {
            int col = bn + n * 16 + lr;
            float bb = bias[col];
            f32x4 v = acc[m][n];
#pragma unroll
            for (int r = 0; r < 4; ++r) {
                float o = v[r] + bb;
                if (RELU) o = fmaxf(o, 0.f);
                if (SCALE) o *= dvr[r];
                if (BF16OUT)
                    ((unsigned short*)Cout)[(size_t)(base_row + r) * 256 + col] = f2bf(o);
                else
                    ((float*)Cout)[(size_t)(base_row + r) * 256 + col] = o;
            }
        }
    }
}

// ---------------------------------------------------------------------------
extern "C" void kernel_launch(void* const* d_in, const int* in_sizes, int n_in,
                              void* d_out, int out_size, void* d_ws, size_t ws_size,
                              hipStream_t stream) {
    const float* x  = (const float*)d_in[0];
    const int*   ei = (const int*)d_in[1];
    const float* W1 = (const float*)d_in[2];
    const float* b1 = (const float*)d_in[3];
    const float* W2 = (const float*)d_in[4];
    const float* b2 = (const float*)d_in[5];
    float* out = (float*)d_out;

    char* w = (char*)d_ws;
    float* dinv            = (float*)(w + 0x0);        // 128 KB
    int*   counts          = (int*)  (w + 0x20000);    // 128 KB
    int*   cursor          = (int*)  (w + 0x40000);    // 128 KB
    int*   offs            = (int*)  (w + 0x60000);    // ~128 KB
    int*   csr             = (int*)  (w + 0x90000);    // 4 MB
    unsigned short* Wt1    = (unsigned short*)(w + 0x4A0000);   // 128 KB
    unsigned short* Wt2    = (unsigned short*)(w + 0x4C0000);   // 128 KB
    unsigned short* xb     = (unsigned short*)(w + 0x500000);   // 16 MB (y1)
    unsigned short* bufA   = (unsigned short*)(w + 0x1500000);  // 16 MB
    unsigned short* bufB   = (unsigned short*)(w + 0x2500000);  // 16 MB (y2)
    unsigned short* bufC   = (unsigned short*)(w + 0x3500000);  // 16 MB (ends 0x4500000)

    hipMemsetAsync(counts, 0, BN_TOT * sizeof(int), stream);
    hipMemsetAsync(cursor, 0, BN_TOT * sizeof(int), stream);

    count_kernel<<<(B * E) / 256, 256, 0, stream>>>(ei, counts);
    scan_kernel<<<B, 1024, 0, stream>>>(counts, offs, dinv);
    fill_kernel<<<(B * E) / 256, 256, 0, stream>>>(ei, offs, cursor, csr);
    prep_w<<<512, 64, 0, stream>>>(W1, W2, Wt1, Wt2);
    xconv_kernel<<<8192, 256, 0, stream>>>(x, xb, dinv);   // y1 = dinv * x

    // layer 1: agg(y1) -> bufA ; y2 = dinv*relu(bufA@W1+b1) -> bufB
    agg_sum<<<8192, 256, 0, stream>>>(xb, bufA, csr, offs, dinv);
    gemm_mfma<true, true, true><<<1024, 256, 0, stream>>>(bufA, Wt1, b1, dinv, bufB);
    // layer 2: agg(y2) -> bufC ; bufC@W2+b2 -> out (f32)
    agg_sum<<<8192, 256, 0, stream>>>(bufB, bufC, csr, offs, dinv);
    gemm_mfma<false, false, false><<<1024, 256, 0, stream>>>(bufC, Wt2, b2, nullptr, out);
}

// Round 5
// 217.068 us; speedup vs baseline: 2.1177x; 1.0822x over previous
//
#include <hip/hip_runtime.h>

// Problem constants (from reference)
constexpr int B = 8;
constexpr int N = 4096;
constexpr int E = 131072;     // 2^17
constexpr int C = 256;
constexpr int BN_TOT = B * N; // 32768

typedef __attribute__((ext_vector_type(8))) short s16x8;
typedef __attribute__((ext_vector_type(8))) unsigned short u16x8;
typedef __attribute__((ext_vector_type(4))) float f32x4;

__device__ __forceinline__ unsigned short f2bf(float f) {
    unsigned u = __float_as_uint(f);
    unsigned r = (u + 0x7FFFu + ((u >> 16) & 1u)) >> 16;   // RNE
    return (unsigned short)r;
}
__device__ __forceinline__ float b2f(unsigned short u) {
    return __uint_as_float(((unsigned)u) << 16);
}

// ---------------------------------------------------------------------------
// K1: count in-degree per (graph, node)
__global__ __launch_bounds__(256) void count_kernel(const int* __restrict__ ei,
                                                    int* __restrict__ counts) {
    int idx = blockIdx.x * 256 + threadIdx.x;   // [0, B*E)
    int b = idx >> 17;
    int e = idx & (E - 1);
    int dst = ei[(size_t)b * 2 * E + E + e];
    atomicAdd(&counts[b * N + dst], 1);
}

// ---------------------------------------------------------------------------
// K2: per-graph exclusive scan of counts -> CSR offsets; dinv = rsqrt(deg+1)
__global__ __launch_bounds__(1024) void scan_kernel(const int* __restrict__ counts,
                                                    int* __restrict__ offs,
                                                    float* __restrict__ dinv) {
    __shared__ int lds[1024];
    int b = blockIdx.x, t = threadIdx.x;
    int base = b * N + t * 4;
    int c0 = counts[base + 0];
    int c1 = counts[base + 1];
    int c2 = counts[base + 2];
    int c3 = counts[base + 3];
    lds[t] = c0 + c1 + c2 + c3;
    __syncthreads();
    for (int s = 1; s < 1024; s <<= 1) {
        int v = 0;
        if (t >= s) v = lds[t - s];
        __syncthreads();
        lds[t] += v;
        __syncthreads();
    }
    int excl = (t == 0) ? 0 : lds[t - 1];
    int ob = b * (N + 1) + t * 4;
    offs[ob + 0] = excl;
    offs[ob + 1] = excl + c0;
    offs[ob + 2] = excl + c0 + c1;
    offs[ob + 3] = excl + c0 + c1 + c2;
    if (t == 1023) offs[b * (N + 1) + N] = lds[1023];
    dinv[base + 0] = rsqrtf((float)(c0 + 1));
    dinv[base + 1] = rsqrtf((float)(c1 + 1));
    dinv[base + 2] = rsqrtf((float)(c2 + 1));
    dinv[base + 3] = rsqrtf((float)(c3 + 1));
}

// ---------------------------------------------------------------------------
// K3: scatter edge sources into CSR slots
__global__ __launch_bounds__(256) void fill_kernel(const int* __restrict__ ei,
                                                   const int* __restrict__ offs,
                                                   int* __restrict__ cursor,
                                                   int* __restrict__ csr) {
    int idx = blockIdx.x * 256 + threadIdx.x;
    int b = idx >> 17;
    int e = idx & (E - 1);
    int src = ei[(size_t)b * 2 * E + e];
    int dst = ei[(size_t)b * 2 * E + E + e];
    int pos = atomicAdd(&cursor[b * N + dst], 1);
    csr[(size_t)b * E + offs[b * (N + 1) + dst] + pos] = src;
}

// ---------------------------------------------------------------------------
// K4: y1 = dinv[row] * x (f32 -> bf16), XCD-pinned per graph
__global__ __launch_bounds__(256) void xconv_kernel(const float* __restrict__ x,
                                                    unsigned short* __restrict__ xb,
                                                    const float* __restrict__ dinv) {
    int bid = blockIdx.x;
    int g = bid & 7;
    int off = bid >> 3;                          // [0,1024)
    size_t base = (size_t)g * (N * C) + (size_t)off * 1024 + threadIdx.x * 4;
    float dv = dinv[g * N + off * 4 + (threadIdx.x >> 6)];
    float4 v = *(const float4*)(x + base);
    ushort4 o;
    o.x = f2bf(dv * v.x); o.y = f2bf(dv * v.y);
    o.z = f2bf(dv * v.z); o.w = f2bf(dv * v.w);
    *(ushort4*)(xb + base) = o;
}

// ---------------------------------------------------------------------------
// K5: W [K][N] f32 -> Wt [N][K] bf16 (transposed)
__global__ __launch_bounds__(64) void prep_w(const float* __restrict__ W1,
                                             const float* __restrict__ W2,
                                             unsigned short* __restrict__ Wt1,
                                             unsigned short* __restrict__ Wt2) {
    int n = blockIdx.x & 255;
    int w = blockIdx.x >> 8;
    const float* W = w ? W2 : W1;
    unsigned short* Wt = w ? Wt2 : Wt1;
#pragma unroll
    for (int i = 0; i < 4; ++i) {
        int k = threadIdx.x + i * 64;
        Wt[n * 256 + k] = f2bf(W[k * 256 + n]);
    }
}

// ---------------------------------------------------------------------------
// K6: norm-free aggregation, TWO EDGES PER WAVE:
//   out[b,v,:] = dinv[v] * ( y[b,v,:] + sum_{u->v} y[b,u,:] )
// Lanes 0-31 process even edges, 32-63 odd edges; 16 B/lane (8 channels).
// Halves combined at the end via __shfl_xor(.,32). 4-pair (8-edge) pipeline.
__global__ __launch_bounds__(256) void agg_sum(const unsigned short* __restrict__ in,
                                               unsigned short* __restrict__ out,
                                               const int* __restrict__ csr,
                                               const int* __restrict__ offs,
                                               const float* __restrict__ dinv) {
    int bid = blockIdx.x;
    int b = bid & 7;                      // XCD-pinned graph
    int v = (bid >> 3) * 4 + (threadIdx.x >> 6);
    int lane = threadIdx.x & 63;
    int half = lane >> 5;                 // 0: even edge, 1: odd edge
    int hl = lane & 31;                   // lane within half: channels [hl*8, hl*8+8)
    const unsigned short* inb = in + (size_t)b * (N * C);
    const unsigned short* base = inb + hl * 8;
    const int* cs = csr + (size_t)b * E;

    int s = offs[b * (N + 1) + v];
    int e = offs[b * (N + 1) + v + 1];

    float acc[8];
    {   // self-loop term: lower half only (upper half zeros to avoid double count)
        u16x8 xv = *(const u16x8*)(inb + (size_t)v * C + hl * 8);
#pragma unroll
        for (int c = 0; c < 8; ++c) acc[c] = half ? 0.f : b2f(xv[c]);
    }

    int np = (e - s) >> 1;               // edge pairs
    int ip = 0;
    if (np >= 4) {
        int u[4];
#pragma unroll
        for (int j = 0; j < 4; ++j) {
            int p0 = cs[s + 2 * j + 0];
            int p1 = cs[s + 2 * j + 1];
            u[j] = half ? p1 : p0;
        }
        for (; ip + 8 <= np; ip += 4) {
            u16x8 f[4];
#pragma unroll
            for (int j = 0; j < 4; ++j) f[j] = *(const u16x8*)(base + (size_t)u[j] * C);
#pragma unroll
            for (int j = 0; j < 4; ++j) {
                int p0 = cs[s + 2 * (ip + 4 + j) + 0];
                int p1 = cs[s + 2 * (ip + 4 + j) + 1];
                u[j] = half ? p1 : p0;
            }
#pragma unroll
            for (int j = 0; j < 4; ++j)
#pragma unroll
                for (int c = 0; c < 8; ++c) acc[c] += b2f(f[j][c]);
        }
        {   // drain last preloaded batch
            u16x8 f[4];
#pragma unroll
            for (int j = 0; j < 4; ++j) f[j] = *(const u16x8*)(base + (size_t)u[j] * C);
#pragma unroll
            for (int j = 0; j < 4; ++j)
#pragma unroll
                for (int c = 0; c < 8; ++c) acc[c] += b2f(f[j][c]);
            ip += 4;
        }
    }
    for (; ip < np; ++ip) {
        int p0 = cs[s + 2 * ip + 0];
        int p1 = cs[s + 2 * ip + 1];
        int u = half ? p1 : p0;
        u16x8 f = *(const u16x8*)(base + (size_t)u * C);
#pragma unroll
        for (int c = 0; c < 8; ++c) acc[c] += b2f(f[c]);
    }
    if ((e - s) & 1) {                   // odd tail edge: lower half only
        int u = cs[e - 1];
        if (!half) {
            u16x8 f = *(const u16x8*)(base + (size_t)u * C);
#pragma unroll
            for (int c = 0; c < 8; ++c) acc[c] += b2f(f[c]);
        }
    }

    // combine halves
#pragma unroll
    for (int c = 0; c < 8; ++c) acc[c] += __shfl_xor(acc[c], 32, 64);

    float dv = dinv[b * N + v];
    if (!half) {
        u16x8 o;
#pragma unroll
        for (int c = 0; c < 8; ++c) o[c] = f2bf(dv * acc[c]);
        *(u16x8*)(out + ((size_t)b * N + v) * C + hl * 8) = o;
    }
}

// ---------------------------------------------------------------------------
// K7: bf16 MFMA GEMM: Cout[M,256] = A[M,256] @ W[256,256] (+bias, opt ReLU,
// opt row-scale by dinv). A bf16 row-major; Wt bf16 TRANSPOSED [N][K].
// 256 thr = 4 waves, tile 128x64, K-chunks of 64; BOTH A and W staged per-chunk
// -> LDS 24 KB -> 4 blocks/CU co-resident (was 48 KB -> 3/CU + 33% tail).
// LDS XOR-swizzled (byte ^= (row&7)<<4).
// C/D layout (HW-verified): col = lane&15, row = (lane>>4)*4 + reg.
template <bool RELU, bool BF16OUT, bool SCALE>
__global__ __launch_bounds__(256) void gemm_mfma(const unsigned short* __restrict__ A,
                                                 const unsigned short* __restrict__ Wt,
                                                 const float* __restrict__ bias,
                                                 const float* __restrict__ dinv,
                                                 void* __restrict__ Cout) {
    __shared__ __align__(16) char lds[24576];
    char* AsB = lds;            // 16 KB: [128 m][64 k] bf16, swizzled
    char* WsB = lds + 16384;    //  8 KB: [64 n][64 k] bf16, swizzled

    int tid = threadIdx.x;
    int bid = blockIdx.x;
    int g = bid & 7;                 // XCD-pinned graph
    int i = bid >> 3;                // [0,128)
    int mloc = i >> 2;               // [0,32)
    int nb = i & 3;                  // [0,4)
    int bm = g * 4096 + mloc * 128;
    int bn = nb * 64;

    const int l = tid & 63;
    const int w = tid >> 6;
    const int lr = l & 15;
    const int lg = l >> 4;

    f32x4 acc[2][4] = {};

    for (int kc = 0; kc < 4; ++kc) {
        __syncthreads();             // protect LDS from prior-iter readers
        // Stage A chunk: [128 rows][64 k] = 1024 x 16B chunks (4/thread).
#pragma unroll
        for (int c = 0; c < 4; ++c) {
            int f = tid + c * 256;
            int row = f >> 3;
            int slot = f & 7;
            s16x8 vv = *(const s16x8*)(A + (size_t)(bm + row) * 256 + kc * 64 + slot * 8);
            *(s16x8*)(AsB + row * 128 + ((slot * 16) ^ ((row & 7) << 4))) = vv;
        }
        // Stage W chunk: [64 rows][64 k] = 512 x 16B chunks (2/thread).
#pragma unroll
        for (int c = 0; c < 2; ++c) {
            int f = tid + c * 256;
            int r = f >> 3;
            int slot = f & 7;
            s16x8 vv = *(const s16x8*)(Wt + (size_t)(bn + r) * 256 + kc * 64 + slot * 8);
            *(s16x8*)(WsB + r * 128 + ((slot * 16) ^ ((r & 7) << 4))) = vv;
        }
        __syncthreads();

#pragma unroll
        for (int ks = 0; ks < 2; ++ks) {
            s16x8 af[2];
#pragma unroll
            for (int m = 0; m < 2; ++m) {
                int row = w * 32 + m * 16 + lr;
                int bir = ks * 64 + lg * 16;          // byte within 128B row
                af[m] = *(const s16x8*)(AsB + row * 128 + (bir ^ ((row & 7) << 4)));
            }
            s16x8 wf[4];
#pragma unroll
            for (int n = 0; n < 4; ++n) {
                int cidx = n * 16 + lr;
                int bir = ks * 64 + lg * 16;
                wf[n] = *(const s16x8*)(WsB + cidx * 128 + (bir ^ ((cidx & 7) << 4)));
            }
#pragma unroll
            for (int m = 0; m < 2; ++m)
#pragma unroll
                for (int n = 0; n < 4; ++n)
                    acc[m][n] = __builtin_amdgcn_mfma_f32_16x16x32_bf16(af[m], wf[n], acc[m][n], 0, 0, 0);
        }
    }

    // Epilogue: D col = lane&15, row = (lane>>4)*4 + reg
#pragma unroll
    for (int m = 0; m < 2; ++m) {
        int base_row = bm + w * 32 + m * 16 + lg * 4;
        float4 dv4 = make_float4(1.f, 1.f, 1.f, 1.f);
        if (SCALE) dv4 = *(const float4*)(dinv + base_row);
        float dvr[4] = {dv4.x, dv4.y, dv4.z, dv4.w};
#pragma unroll
        for (int n = 0; n < 4; ++n) {
            int col = bn + n * 16 + lr;
            float bb = bias[col];
            f32x4 v = acc[m][n];
#pragma unroll
            for (int r = 0; r < 4; ++r) {
                float o = v[r] + bb;
                if (RELU) o = fmaxf(o, 0.f);
                if (SCALE) o *= dvr[r];
                if (BF16OUT)
                    ((unsigned short*)Cout)[(size_t)(base_row + r) * 256 + col] = f2bf(o);
                else
                    ((float*)Cout)[(size_t)(base_row + r) * 256 + col] = o;
            }
        }
    }
}

// ---------------------------------------------------------------------------
extern "C" void kernel_launch(void* const* d_in, const int* in_sizes, int n_in,
                              void* d_out, int out_size, void* d_ws, size_t ws_size,
                              hipStream_t stream) {
    const float* x  = (const float*)d_in[0];
    const int*   ei = (const int*)d_in[1];
    const float* W1 = (const float*)d_in[2];
    const float* b1 = (const float*)d_in[3];
    const float* W2 = (const float*)d_in[4];
    const float* b2 = (const float*)d_in[5];
    float* out = (float*)d_out;

    char* w = (char*)d_ws;
    float* dinv            = (float*)(w + 0x0);        // 128 KB
    int*   counts          = (int*)  (w + 0x20000);    // 128 KB
    int*   cursor          = (int*)  (w + 0x40000);    // 128 KB
    int*   offs            = (int*)  (w + 0x60000);    // ~128 KB
    int*   csr             = (int*)  (w + 0x90000);    // 4 MB
    unsigned short* Wt1    = (unsigned short*)(w + 0x4A0000);   // 128 KB
    unsigned short* Wt2    = (unsigned short*)(w + 0x4C0000);   // 128 KB
    unsigned short* xb     = (unsigned short*)(w + 0x500000);   // 16 MB (y1)
    unsigned short* bufA   = (unsigned short*)(w + 0x1500000);  // 16 MB
    unsigned short* bufB   = (unsigned short*)(w + 0x2500000);  // 16 MB (y2)
    unsigned short* bufC   = (unsigned short*)(w + 0x3500000);  // 16 MB (ends 0x4500000)

    hipMemsetAsync(counts, 0, BN_TOT * sizeof(int), stream);
    hipMemsetAsync(cursor, 0, BN_TOT * sizeof(int), stream);

    count_kernel<<<(B * E) / 256, 256, 0, stream>>>(ei, counts);
    scan_kernel<<<B, 1024, 0, stream>>>(counts, offs, dinv);
    fill_kernel<<<(B * E) / 256, 256, 0, stream>>>(ei, offs, cursor, csr);
    prep_w<<<512, 64, 0, stream>>>(W1, W2, Wt1, Wt2);
    xconv_kernel<<<8192, 256, 0, stream>>>(x, xb, dinv);   // y1 = dinv * x

    // layer 1: agg(y1) -> bufA ; y2 = dinv*relu(bufA@W1+b1) -> bufB
    agg_sum<<<8192, 256, 0, stream>>>(xb, bufA, csr, offs, dinv);
    gemm_mfma<true, true, true><<<1024, 256, 0, stream>>>(bufA, Wt1, b1, dinv, bufB);
    // layer 2: agg(y2) -> bufC ; bufC@W2+b2 -> out (f32)
    agg_sum<<<8192, 256, 0, stream>>>(bufB, bufC, csr, offs, dinv);
    gemm_mfma<false, false, false><<<1024, 256, 0, stream>>>(bufC, Wt2, b2, nullptr, out);
}

// Round 6
// 169.745 us; speedup vs baseline: 2.7081x; 1.2788x over previous
//
#include <hip/hip_runtime.h>

// Problem constants (from reference)
constexpr int B = 8;
constexpr int N = 4096;
constexpr int E = 131072;     // 2^17
constexpr int C = 256;
constexpr int BN_TOT = B * N; // 32768

typedef __attribute__((ext_vector_type(8))) short s16x8;
typedef __attribute__((ext_vector_type(8))) unsigned short u16x8;
typedef __attribute__((ext_vector_type(4))) float f32x4;

__device__ __forceinline__ unsigned short f2bf(float f) {
    unsigned u = __float_as_uint(f);
    unsigned r = (u + 0x7FFFu + ((u >> 16) & 1u)) >> 16;   // RNE
    return (unsigned short)r;
}
__device__ __forceinline__ float b2f(unsigned short u) {
    return __uint_as_float(((unsigned)u) << 16);
}

// ---------------------------------------------------------------------------
// K1: count in-degree per (graph, node); atomic return value IS the edge's
// rank within its dst bucket -> store packed (dst | rank<<12) for fill.
// XCD-pinned: g = bid&7 so each graph's count lines stay on one XCD.
__global__ __launch_bounds__(256) void count_kernel(const int* __restrict__ ei,
                                                    int* __restrict__ counts,
                                                    int* __restrict__ rankp) {
    int bid = blockIdx.x;
    int g = bid & 7;
    int e = (bid >> 3) * 256 + threadIdx.x;       // [0, E)
    int dst = ei[(size_t)g * 2 * E + E + e];
    int r = atomicAdd(&counts[g * N + dst], 1);
    rankp[(size_t)g * E + e] = dst | (r << 12);   // rank < 2^17 fits
}

// ---------------------------------------------------------------------------
// K2: per-graph exclusive scan of counts -> CSR offsets; dinv = rsqrt(deg+1)
__global__ __launch_bounds__(1024) void scan_kernel(const int* __restrict__ counts,
                                                    int* __restrict__ offs,
                                                    float* __restrict__ dinv) {
    __shared__ int lds[1024];
    int b = blockIdx.x, t = threadIdx.x;
    int base = b * N + t * 4;
    int c0 = counts[base + 0];
    int c1 = counts[base + 1];
    int c2 = counts[base + 2];
    int c3 = counts[base + 3];
    lds[t] = c0 + c1 + c2 + c3;
    __syncthreads();
    for (int s = 1; s < 1024; s <<= 1) {
        int v = 0;
        if (t >= s) v = lds[t - s];
        __syncthreads();
        lds[t] += v;
        __syncthreads();
    }
    int excl = (t == 0) ? 0 : lds[t - 1];
    int ob = b * (N + 1) + t * 4;
    offs[ob + 0] = excl;
    offs[ob + 1] = excl + c0;
    offs[ob + 2] = excl + c0 + c1;
    offs[ob + 3] = excl + c0 + c1 + c2;
    if (t == 1023) offs[b * (N + 1) + N] = lds[1023];
    dinv[base + 0] = rsqrtf((float)(c0 + 1));
    dinv[base + 1] = rsqrtf((float)(c1 + 1));
    dinv[base + 2] = rsqrtf((float)(c2 + 1));
    dinv[base + 3] = rsqrtf((float)(c3 + 1));
}

// ---------------------------------------------------------------------------
// K3: scatter edge sources into CSR slots. Atomic-free: rank precomputed in
// count_kernel. XCD-pinned; offs reads hit the local L2.
__global__ __launch_bounds__(256) void fill_kernel(const int* __restrict__ ei,
                                                   const int* __restrict__ offs,
                                                   const int* __restrict__ rankp,
                                                   int* __restrict__ csr) {
    int bid = blockIdx.x;
    int g = bid & 7;
    int e = (bid >> 3) * 256 + threadIdx.x;
    int src = ei[(size_t)g * 2 * E + e];
    int pk = rankp[(size_t)g * E + e];
    int dst = pk & 4095;
    int r = pk >> 12;
    csr[(size_t)g * E + offs[g * (N + 1) + dst] + r] = src;
}

// ---------------------------------------------------------------------------
// K4: y1 = dinv[row] * x (f32 -> bf16), XCD-pinned per graph
__global__ __launch_bounds__(256) void xconv_kernel(const float* __restrict__ x,
                                                    unsigned short* __restrict__ xb,
                                                    const float* __restrict__ dinv) {
    int bid = blockIdx.x;
    int g = bid & 7;
    int off = bid >> 3;                          // [0,1024)
    size_t base = (size_t)g * (N * C) + (size_t)off * 1024 + threadIdx.x * 4;
    float dv = dinv[g * N + off * 4 + (threadIdx.x >> 6)];
    float4 v = *(const float4*)(x + base);
    ushort4 o;
    o.x = f2bf(dv * v.x); o.y = f2bf(dv * v.y);
    o.z = f2bf(dv * v.z); o.w = f2bf(dv * v.w);
    *(ushort4*)(xb + base) = o;
}

// ---------------------------------------------------------------------------
// K5: W [K][N] f32 -> Wt [N][K] bf16 (transposed)
__global__ __launch_bounds__(64) void prep_w(const float* __restrict__ W1,
                                             const float* __restrict__ W2,
                                             unsigned short* __restrict__ Wt1,
                                             unsigned short* __restrict__ Wt2) {
    int n = blockIdx.x & 255;
    int w = blockIdx.x >> 8;
    const float* W = w ? W2 : W1;
    unsigned short* Wt = w ? Wt2 : Wt1;
#pragma unroll
    for (int i = 0; i < 4; ++i) {
        int k = threadIdx.x + i * 64;
        Wt[n * 256 + k] = f2bf(W[k * 256 + n]);
    }
}

// ---------------------------------------------------------------------------
// K6: norm-free aggregation, TWO EDGES PER WAVE:
//   out[b,v,:] = dinv[v] * ( y[b,v,:] + sum_{u->v} y[b,u,:] )
// Lanes 0-31 process even edges, 32-63 odd edges; 16 B/lane (8 channels).
// Halves combined at the end via __shfl_xor(.,32). 4-pair (8-edge) pipeline.
__global__ __launch_bounds__(256) void agg_sum(const unsigned short* __restrict__ in,
                                               unsigned short* __restrict__ out,
                                               const int* __restrict__ csr,
                                               const int* __restrict__ offs,
                                               const float* __restrict__ dinv) {
    int bid = blockIdx.x;
    int b = bid & 7;                      // XCD-pinned graph
    int v = (bid >> 3) * 4 + (threadIdx.x >> 6);
    int lane = threadIdx.x & 63;
    int half = lane >> 5;                 // 0: even edge, 1: odd edge
    int hl = lane & 31;                   // lane within half: channels [hl*8, hl*8+8)
    const unsigned short* inb = in + (size_t)b * (N * C);
    const unsigned short* base = inb + hl * 8;
    const int* cs = csr + (size_t)b * E;

    int s = offs[b * (N + 1) + v];
    int e = offs[b * (N + 1) + v + 1];

    float acc[8];
    {   // self-loop term: lower half only (upper half zeros to avoid double count)
        u16x8 xv = *(const u16x8*)(inb + (size_t)v * C + hl * 8);
#pragma unroll
        for (int c = 0; c < 8; ++c) acc[c] = half ? 0.f : b2f(xv[c]);
    }

    int np = (e - s) >> 1;               // edge pairs
    int ip = 0;
    if (np >= 4) {
        int u[4];
#pragma unroll
        for (int j = 0; j < 4; ++j) {
            int p0 = cs[s + 2 * j + 0];
            int p1 = cs[s + 2 * j + 1];
            u[j] = half ? p1 : p0;
        }
        for (; ip + 8 <= np; ip += 4) {
            u16x8 f[4];
#pragma unroll
            for (int j = 0; j < 4; ++j) f[j] = *(const u16x8*)(base + (size_t)u[j] * C);
#pragma unroll
            for (int j = 0; j < 4; ++j) {
                int p0 = cs[s + 2 * (ip + 4 + j) + 0];
                int p1 = cs[s + 2 * (ip + 4 + j) + 1];
                u[j] = half ? p1 : p0;
            }
#pragma unroll
            for (int j = 0; j < 4; ++j)
#pragma unroll
                for (int c = 0; c < 8; ++c) acc[c] += b2f(f[j][c]);
        }
        {   // drain last preloaded batch
            u16x8 f[4];
#pragma unroll
            for (int j = 0; j < 4; ++j) f[j] = *(const u16x8*)(base + (size_t)u[j] * C);
#pragma unroll
            for (int j = 0; j < 4; ++j)
#pragma unroll
                for (int c = 0; c < 8; ++c) acc[c] += b2f(f[j][c]);
            ip += 4;
        }
    }
    for (; ip < np; ++ip) {
        int p0 = cs[s + 2 * ip + 0];
        int p1 = cs[s + 2 * ip + 1];
        int u = half ? p1 : p0;
        u16x8 f = *(const u16x8*)(base + (size_t)u * C);
#pragma unroll
        for (int c = 0; c < 8; ++c) acc[c] += b2f(f[c]);
    }
    if ((e - s) & 1) {                   // odd tail edge: lower half only
        int u = cs[e - 1];
        if (!half) {
            u16x8 f = *(const u16x8*)(base + (size_t)u * C);
#pragma unroll
            for (int c = 0; c < 8; ++c) acc[c] += b2f(f[c]);
        }
    }

    // combine halves
#pragma unroll
    for (int c = 0; c < 8; ++c) acc[c] += __shfl_xor(acc[c], 32, 64);

    float dv = dinv[b * N + v];
    if (!half) {
        u16x8 o;
#pragma unroll
        for (int c = 0; c < 8; ++c) o[c] = f2bf(dv * acc[c]);
        *(u16x8*)(out + ((size_t)b * N + v) * C + hl * 8) = o;
    }
}

// ---------------------------------------------------------------------------
// K7: bf16 MFMA GEMM: Cout[M,256] = A[M,256] @ W[256,256] (+bias, opt ReLU,
// opt row-scale by dinv). A bf16 row-major; Wt bf16 TRANSPOSED [N][K].
// 256 thr = 4 waves, tile 128x64, K-chunks of 64; LDS 24 KB -> 4 blocks/CU.
// LDS XOR-swizzled (byte ^= (row&7)<<4).
// C/D layout (HW-verified): col = lane&15, row = (lane>>4)*4 + reg.
template <bool RELU, bool BF16OUT, bool SCALE>
__global__ __launch_bounds__(256) void gemm_mfma(const unsigned short* __restrict__ A,
                                                 const unsigned short* __restrict__ Wt,
                                                 const float* __restrict__ bias,
                                                 const float* __restrict__ dinv,
                                                 void* __restrict__ Cout) {
    __shared__ __align__(16) char lds[24576];
    char* AsB = lds;            // 16 KB: [128 m][64 k] bf16, swizzled
    char* WsB = lds + 16384;    //  8 KB: [64 n][64 k] bf16, swizzled

    int tid = threadIdx.x;
    int bid = blockIdx.x;
    int g = bid & 7;                 // XCD-pinned graph
    int i = bid >> 3;                // [0,128)
    int mloc = i >> 2;               // [0,32)
    int nb = i & 3;                  // [0,4)
    int bm = g * 4096 + mloc * 128;
    int bn = nb * 64;

    const int l = tid & 63;
    const int w = tid >> 6;
    const int lr = l & 15;
    const int lg = l >> 4;

    f32x4 acc[2][4] = {};

    for (int kc = 0; kc < 4; ++kc) {
        __syncthreads();             // protect LDS from prior-iter readers
        // Stage A chunk: [128 rows][64 k] = 1024 x 16B chunks (4/thread).
#pragma unroll
        for (int c = 0; c < 4; ++c) {
            int f = tid + c * 256;
            int row = f >> 3;
            int slot = f & 7;
            s16x8 vv = *(const s16x8*)(A + (size_t)(bm + row) * 256 + kc * 64 + slot * 8);
            *(s16x8*)(AsB + row * 128 + ((slot * 16) ^ ((row & 7) << 4))) = vv;
        }
        // Stage W chunk: [64 rows][64 k] = 512 x 16B chunks (2/thread).
#pragma unroll
        for (int c = 0; c < 2; ++c) {
            int f = tid + c * 256;
            int r = f >> 3;
            int slot = f & 7;
            s16x8 vv = *(const s16x8*)(Wt + (size_t)(bn + r) * 256 + kc * 64 + slot * 8);
            *(s16x8*)(WsB + r * 128 + ((slot * 16) ^ ((r & 7) << 4))) = vv;
        }
        __syncthreads();

#pragma unroll
        for (int ks = 0; ks < 2; ++ks) {
            s16x8 af[2];
#pragma unroll
            for (int m = 0; m < 2; ++m) {
                int row = w * 32 + m * 16 + lr;
                int bir = ks * 64 + lg * 16;          // byte within 128B row
                af[m] = *(const s16x8*)(AsB + row * 128 + (bir ^ ((row & 7) << 4)));
            }
            s16x8 wf[4];
#pragma unroll
            for (int n = 0; n < 4; ++n) {
                int cidx = n * 16 + lr;
                int bir = ks * 64 + lg * 16;
                wf[n] = *(const s16x8*)(WsB + cidx * 128 + (bir ^ ((cidx & 7) << 4)));
            }
#pragma unroll
            for (int m = 0; m < 2; ++m)
#pragma unroll
                for (int n = 0; n < 4; ++n)
                    acc[m][n] = __builtin_amdgcn_mfma_f32_16x16x32_bf16(af[m], wf[n], acc[m][n], 0, 0, 0);
        }
    }

    // Epilogue: D col = lane&15, row = (lane>>4)*4 + reg
#pragma unroll
    for (int m = 0; m < 2; ++m) {
        int base_row = bm + w * 32 + m * 16 + lg * 4;
        float4 dv4 = make_float4(1.f, 1.f, 1.f, 1.f);
        if (SCALE) dv4 = *(const float4*)(dinv + base_row);
        float dvr[4] = {dv4.x, dv4.y, dv4.z, dv4.w};
#pragma unroll
        for (int n = 0; n < 4; ++n) {
            int col = bn + n * 16 + lr;
            float bb = bias[col];
            f32x4 v = acc[m][n];
#pragma unroll
            for (int r = 0; r < 4; ++r) {
                float o = v[r] + bb;
                if (RELU) o = fmaxf(o, 0.f);
                if (SCALE) o *= dvr[r];
                if (BF16OUT)
                    ((unsigned short*)Cout)[(size_t)(base_row + r) * 256 + col] = f2bf(o);
                else
                    ((float*)Cout)[(size_t)(base_row + r) * 256 + col] = o;
            }
        }
    }
}

// ---------------------------------------------------------------------------
extern "C" void kernel_launch(void* const* d_in, const int* in_sizes, int n_in,
                              void* d_out, int out_size, void* d_ws, size_t ws_size,
                              hipStream_t stream) {
    const float* x  = (const float*)d_in[0];
    const int*   ei = (const int*)d_in[1];
    const float* W1 = (const float*)d_in[2];
    const float* b1 = (const float*)d_in[3];
    const float* W2 = (const float*)d_in[4];
    const float* b2 = (const float*)d_in[5];
    float* out = (float*)d_out;

    char* w = (char*)d_ws;
    float* dinv            = (float*)(w + 0x0);        // 128 KB
    int*   counts          = (int*)  (w + 0x20000);    // 128 KB
    int*   offs            = (int*)  (w + 0x60000);    // ~128 KB
    int*   csr             = (int*)  (w + 0x90000);    // 4 MB
    unsigned short* Wt1    = (unsigned short*)(w + 0x4A0000);   // 128 KB
    unsigned short* Wt2    = (unsigned short*)(w + 0x4C0000);   // 128 KB
    unsigned short* xb     = (unsigned short*)(w + 0x500000);   // 16 MB (y1)
    unsigned short* bufA   = (unsigned short*)(w + 0x1500000);  // 16 MB
    unsigned short* bufB   = (unsigned short*)(w + 0x2500000);  // 16 MB (y2)
    unsigned short* bufC   = (unsigned short*)(w + 0x3500000);  // 16 MB (ends 0x4500000)
    int*   rankp           = (int*)bufC;   // alias: rank buffer dead before bufC is written

    hipMemsetAsync(counts, 0, BN_TOT * sizeof(int), stream);

    count_kernel<<<(B * E) / 256, 256, 0, stream>>>(ei, counts, rankp);
    scan_kernel<<<B, 1024, 0, stream>>>(counts, offs, dinv);
    fill_kernel<<<(B * E) / 256, 256, 0, stream>>>(ei, offs, rankp, csr);
    prep_w<<<512, 64, 0, stream>>>(W1, W2, Wt1, Wt2);
    xconv_kernel<<<8192, 256, 0, stream>>>(x, xb, dinv);   // y1 = dinv * x

    // layer 1: agg(y1) -> bufA ; y2 = dinv*relu(bufA@W1+b1) -> bufB
    agg_sum<<<8192, 256, 0, stream>>>(xb, bufA, csr, offs, dinv);
    gemm_mfma<true, true, true><<<1024, 256, 0, stream>>>(bufA, Wt1, b1, dinv, bufB);
    // layer 2: agg(y2) -> bufC ; bufC@W2+b2 -> out (f32)
    agg_sum<<<8192, 256, 0, stream>>>(bufB, bufC, csr, offs, dinv);
    gemm_mfma<false, false, false><<<1024, 256, 0, stream>>>(bufC, Wt2, b2, nullptr, out);
}

// Round 7
// 168.083 us; speedup vs baseline: 2.7349x; 1.0099x over previous
//
#include <hip/hip_runtime.h>

// Problem constants (from reference)
constexpr int B = 8;
constexpr int N = 4096;
constexpr int E = 131072;     // 2^17
constexpr int C = 256;
constexpr int BN_TOT = B * N; // 32768

typedef __attribute__((ext_vector_type(8))) short s16x8;
typedef __attribute__((ext_vector_type(4))) float f32x4;

__device__ __forceinline__ unsigned short f2bf(float f) {
    unsigned u = __float_as_uint(f);
    unsigned r = (u + 0x7FFFu + ((u >> 16) & 1u)) >> 16;   // RNE
    return (unsigned short)r;
}
__device__ __forceinline__ float b2f(unsigned short u) {
    return __uint_as_float(((unsigned)u) << 16);
}
// unpack 2 packed bf16 (u32) -> 2 f32: low ch = q<<16, high ch = q & 0xFFFF0000
__device__ __forceinline__ void acc2(float2& a, unsigned q) {
    a.x += __uint_as_float(q << 16);
    a.y += __uint_as_float(q & 0xFFFF0000u);
}
__device__ __forceinline__ float2 unpk(unsigned q) {
    return make_float2(__uint_as_float(q << 16), __uint_as_float(q & 0xFFFF0000u));
}

// ---------------------------------------------------------------------------
// K0: zero counts (the rocclr fillBuffer kernel took 41 us at 9% occupancy!)
__global__ __launch_bounds__(256) void zero_kernel(int4* __restrict__ p) {
    p[blockIdx.x * 256 + threadIdx.x] = make_int4(0, 0, 0, 0);
}

// ---------------------------------------------------------------------------
// K1: count in-degree per (graph, node); atomic return value IS the edge's
// rank within its dst bucket -> store packed (dst | rank<<12) for fill.
__global__ __launch_bounds__(256) void count_kernel(const int* __restrict__ ei,
                                                    int* __restrict__ counts,
                                                    int* __restrict__ rankp) {
    int bid = blockIdx.x;
    int g = bid & 7;
    int e = (bid >> 3) * 256 + threadIdx.x;       // [0, E)
    int dst = ei[(size_t)g * 2 * E + E + e];
    int r = atomicAdd(&counts[g * N + dst], 1);
    rankp[(size_t)g * E + e] = dst | (r << 12);   // rank < 2^17 fits
}

// ---------------------------------------------------------------------------
// K2: per-graph exclusive scan of counts -> CSR offsets; dinv = rsqrt(deg+1)
__global__ __launch_bounds__(1024) void scan_kernel(const int* __restrict__ counts,
                                                    int* __restrict__ offs,
                                                    float* __restrict__ dinv) {
    __shared__ int lds[1024];
    int b = blockIdx.x, t = threadIdx.x;
    int base = b * N + t * 4;
    int c0 = counts[base + 0];
    int c1 = counts[base + 1];
    int c2 = counts[base + 2];
    int c3 = counts[base + 3];
    lds[t] = c0 + c1 + c2 + c3;
    __syncthreads();
    for (int s = 1; s < 1024; s <<= 1) {
        int v = 0;
        if (t >= s) v = lds[t - s];
        __syncthreads();
        lds[t] += v;
        __syncthreads();
    }
    int excl = (t == 0) ? 0 : lds[t - 1];
    int ob = b * (N + 1) + t * 4;
    offs[ob + 0] = excl;
    offs[ob + 1] = excl + c0;
    offs[ob + 2] = excl + c0 + c1;
    offs[ob + 3] = excl + c0 + c1 + c2;
    if (t == 1023) offs[b * (N + 1) + N] = lds[1023];
    dinv[base + 0] = rsqrtf((float)(c0 + 1));
    dinv[base + 1] = rsqrtf((float)(c1 + 1));
    dinv[base + 2] = rsqrtf((float)(c2 + 1));
    dinv[base + 3] = rsqrtf((float)(c3 + 1));
}

// ---------------------------------------------------------------------------
// K3: scatter edge sources into CSR slots. Atomic-free (rank precomputed).
__global__ __launch_bounds__(256) void fill_kernel(const int* __restrict__ ei,
                                                   const int* __restrict__ offs,
                                                   const int* __restrict__ rankp,
                                                   int* __restrict__ csr) {
    int bid = blockIdx.x;
    int g = bid & 7;
    int e = (bid >> 3) * 256 + threadIdx.x;
    int src = ei[(size_t)g * 2 * E + e];
    int pk = rankp[(size_t)g * E + e];
    int dst = pk & 4095;
    int r = pk >> 12;
    csr[(size_t)g * E + offs[g * (N + 1) + dst] + r] = src;
}

// ---------------------------------------------------------------------------
// K4: y1 = dinv[row] * x (f32 -> bf16), XCD-pinned per graph
__global__ __launch_bounds__(256) void xconv_kernel(const float* __restrict__ x,
                                                    unsigned short* __restrict__ xb,
                                                    const float* __restrict__ dinv) {
    int bid = blockIdx.x;
    int g = bid & 7;
    int off = bid >> 3;                          // [0,1024)
    size_t base = (size_t)g * (N * C) + (size_t)off * 1024 + threadIdx.x * 4;
    float dv = dinv[g * N + off * 4 + (threadIdx.x >> 6)];
    float4 v = *(const float4*)(x + base);
    ushort4 o;
    o.x = f2bf(dv * v.x); o.y = f2bf(dv * v.y);
    o.z = f2bf(dv * v.z); o.w = f2bf(dv * v.w);
    *(ushort4*)(xb + base) = o;
}

// ---------------------------------------------------------------------------
// K5: W [K][N] f32 -> Wt [N][K] bf16 (transposed)
__global__ __launch_bounds__(64) void prep_w(const float* __restrict__ W1,
                                             const float* __restrict__ W2,
                                             unsigned short* __restrict__ Wt1,
                                             unsigned short* __restrict__ Wt2) {
    int n = blockIdx.x & 255;
    int w = blockIdx.x >> 8;
    const float* W = w ? W2 : W1;
    unsigned short* Wt = w ? Wt2 : Wt1;
#pragma unroll
    for (int i = 0; i < 4; ++i) {
        int k = threadIdx.x + i * 64;
        Wt[n * 256 + k] = f2bf(W[k * 256 + n]);
    }
}

// ---------------------------------------------------------------------------
// K6: norm-free aggregation, TWO EDGES PER WAVE, u32-unpack accumulate:
//   out[b,v,:] = dinv[v] * ( y[b,v,:] + sum_{u->v} y[b,u,:] )
// Lanes 0-31 process even edges, 32-63 odd edges; 16 B/lane (8 channels as
// 4 packed u32). Unpack: f_hi = q & 0xFFFF0000 (free bf16->f32), f_lo = q<<16.
// float2 accumulators encourage v_pk_add_f32. Halves combined via shfl_xor(32).
__global__ __launch_bounds__(256) void agg_sum(const unsigned short* __restrict__ in,
                                               unsigned short* __restrict__ out,
                                               const int* __restrict__ csr,
                                               const int* __restrict__ offs,
                                               const float* __restrict__ dinv) {
    int bid = blockIdx.x;
    int b = bid & 7;                      // XCD-pinned graph
    int v = (bid >> 3) * 4 + (threadIdx.x >> 6);
    int lane = threadIdx.x & 63;
    int half = lane >> 5;                 // 0: even edge, 1: odd edge
    int hl = lane & 31;                   // channels [hl*8, hl*8+8)
    const unsigned short* inb = in + (size_t)b * (N * C);
    const unsigned short* base = inb + hl * 8;
    const int* cs = csr + (size_t)b * E;

    int s = offs[b * (N + 1) + v];
    int e = offs[b * (N + 1) + v + 1];

    float2 acc[4];
    {   // self-loop term: lower half only (upper half zeros to avoid double count)
        uint4 xv = *(const uint4*)(inb + (size_t)v * C + hl * 8);
        if (half) {
            acc[0] = acc[1] = acc[2] = acc[3] = make_float2(0.f, 0.f);
        } else {
            acc[0] = unpk(xv.x); acc[1] = unpk(xv.y);
            acc[2] = unpk(xv.z); acc[3] = unpk(xv.w);
        }
    }

    int np = (e - s) >> 1;               // edge pairs
    int ip = 0;
    if (np >= 4) {
        int u[4];
#pragma unroll
        for (int j = 0; j < 4; ++j) {
            int p0 = cs[s + 2 * j + 0];
            int p1 = cs[s + 2 * j + 1];
            u[j] = half ? p1 : p0;
        }
        for (; ip + 8 <= np; ip += 4) {
            uint4 f[4];
#pragma unroll
            for (int j = 0; j < 4; ++j) f[j] = *(const uint4*)(base + (size_t)u[j] * C);
#pragma unroll
            for (int j = 0; j < 4; ++j) {
                int p0 = cs[s + 2 * (ip + 4 + j) + 0];
                int p1 = cs[s + 2 * (ip + 4 + j) + 1];
                u[j] = half ? p1 : p0;
            }
#pragma unroll
            for (int j = 0; j < 4; ++j) {
                acc2(acc[0], f[j].x); acc2(acc[1], f[j].y);
                acc2(acc[2], f[j].z); acc2(acc[3], f[j].w);
            }
        }
        {   // drain last preloaded batch
            uint4 f[4];
#pragma unroll
            for (int j = 0; j < 4; ++j) f[j] = *(const uint4*)(base + (size_t)u[j] * C);
#pragma unroll
            for (int j = 0; j < 4; ++j) {
                acc2(acc[0], f[j].x); acc2(acc[1], f[j].y);
                acc2(acc[2], f[j].z); acc2(acc[3], f[j].w);
            }
            ip += 4;
        }
    }
    for (; ip < np; ++ip) {
        int p0 = cs[s + 2 * ip + 0];
        int p1 = cs[s + 2 * ip + 1];
        int u = half ? p1 : p0;
        uint4 f = *(const uint4*)(base + (size_t)u * C);
        acc2(acc[0], f.x); acc2(acc[1], f.y); acc2(acc[2], f.z); acc2(acc[3], f.w);
    }
    if ((e - s) & 1) {                   // odd tail edge: lower half only
        int u = cs[e - 1];
        if (!half) {
            uint4 f = *(const uint4*)(base + (size_t)u * C);
            acc2(acc[0], f.x); acc2(acc[1], f.y); acc2(acc[2], f.z); acc2(acc[3], f.w);
        }
    }

    // combine halves
#pragma unroll
    for (int c = 0; c < 4; ++c) {
        acc[c].x += __shfl_xor(acc[c].x, 32, 64);
        acc[c].y += __shfl_xor(acc[c].y, 32, 64);
    }

    float dv = dinv[b * N + v];
    if (!half) {
        ushort4 o01, o23;
        o01.x = f2bf(dv * acc[0].x); o01.y = f2bf(dv * acc[0].y);
        o01.z = f2bf(dv * acc[1].x); o01.w = f2bf(dv * acc[1].y);
        o23.x = f2bf(dv * acc[2].x); o23.y = f2bf(dv * acc[2].y);
        o23.z = f2bf(dv * acc[3].x); o23.w = f2bf(dv * acc[3].y);
        unsigned short* op = out + ((size_t)b * N + v) * C + hl * 8;
        *(ushort4*)(op) = o01;
        *(ushort4*)(op + 4) = o23;
    }
}

// ---------------------------------------------------------------------------
// K7: bf16 MFMA GEMM: Cout[M,256] = A[M,256] @ W[256,256] (+bias, opt ReLU,
// opt row-scale by dinv). A bf16 row-major; Wt bf16 TRANSPOSED [N][K].
// 256 thr = 4 waves, tile 128x64, K-chunks of 64; LDS 24 KB -> 4 blocks/CU.
// LDS XOR-swizzled (byte ^= (row&7)<<4).
// C/D layout (HW-verified): col = lane&15, row = (lane>>4)*4 + reg.
template <bool RELU, bool BF16OUT, bool SCALE>
__global__ __launch_bounds__(256) void gemm_mfma(const unsigned short* __restrict__ A,
                                                 const unsigned short* __restrict__ Wt,
                                                 const float* __restrict__ bias,
                                                 const float* __restrict__ dinv,
                                                 void* __restrict__ Cout) {
    __shared__ __align__(16) char lds[24576];
    char* AsB = lds;            // 16 KB: [128 m][64 k] bf16, swizzled
    char* WsB = lds + 16384;    //  8 KB: [64 n][64 k] bf16, swizzled

    int tid = threadIdx.x;
    int bid = blockIdx.x;
    int g = bid & 7;                 // XCD-pinned graph
    int i = bid >> 3;                // [0,128)
    int mloc = i >> 2;               // [0,32)
    int nb = i & 3;                  // [0,4)
    int bm = g * 4096 + mloc * 128;
    int bn = nb * 64;

    const int l = tid & 63;
    const int w = tid >> 6;
    const int lr = l & 15;
    const int lg = l >> 4;

    f32x4 acc[2][4] = {};

    for (int kc = 0; kc < 4; ++kc) {
        __syncthreads();             // protect LDS from prior-iter readers
        // Stage A chunk: [128 rows][64 k] = 1024 x 16B chunks (4/thread).
#pragma unroll
        for (int c = 0; c < 4; ++c) {
            int f = tid + c * 256;
            int row = f >> 3;
            int slot = f & 7;
            s16x8 vv = *(const s16x8*)(A + (size_t)(bm + row) * 256 + kc * 64 + slot * 8);
            *(s16x8*)(AsB + row * 128 + ((slot * 16) ^ ((row & 7) << 4))) = vv;
        }
        // Stage W chunk: [64 rows][64 k] = 512 x 16B chunks (2/thread).
#pragma unroll
        for (int c = 0; c < 2; ++c) {
            int f = tid + c * 256;
            int r = f >> 3;
            int slot = f & 7;
            s16x8 vv = *(const s16x8*)(Wt + (size_t)(bn + r) * 256 + kc * 64 + slot * 8);
            *(s16x8*)(WsB + r * 128 + ((slot * 16) ^ ((r & 7) << 4))) = vv;
        }
        __syncthreads();

#pragma unroll
        for (int ks = 0; ks < 2; ++ks) {
            s16x8 af[2];
#pragma unroll
            for (int m = 0; m < 2; ++m) {
                int row = w * 32 + m * 16 + lr;
                int bir = ks * 64 + lg * 16;          // byte within 128B row
                af[m] = *(const s16x8*)(AsB + row * 128 + (bir ^ ((row & 7) << 4)));
            }
            s16x8 wf[4];
#pragma unroll
            for (int n = 0; n < 4; ++n) {
                int cidx = n * 16 + lr;
                int bir = ks * 64 + lg * 16;
                wf[n] = *(const s16x8*)(WsB + cidx * 128 + (bir ^ ((cidx & 7) << 4)));
            }
#pragma unroll
            for (int m = 0; m < 2; ++m)
#pragma unroll
                for (int n = 0; n < 4; ++n)
                    acc[m][n] = __builtin_amdgcn_mfma_f32_16x16x32_bf16(af[m], wf[n], acc[m][n], 0, 0, 0);
        }
    }

    // Epilogue: D col = lane&15, row = (lane>>4)*4 + reg
#pragma unroll
    for (int m = 0; m < 2; ++m) {
        int base_row = bm + w * 32 + m * 16 + lg * 4;
        float4 dv4 = make_float4(1.f, 1.f, 1.f, 1.f);
        if (SCALE) dv4 = *(const float4*)(dinv + base_row);
        float dvr[4] = {dv4.x, dv4.y, dv4.z, dv4.w};
#pragma unroll
        for (int n = 0; n < 4; ++n) {
            int col = bn + n * 16 + lr;
            float bb = bias[col];
            f32x4 v = acc[m][n];
#pragma unroll
            for (int r = 0; r < 4; ++r) {
                float o = v[r] + bb;
                if (RELU) o = fmaxf(o, 0.f);
                if (SCALE) o *= dvr[r];
                if (BF16OUT)
                    ((unsigned short*)Cout)[(size_t)(base_row + r) * 256 + col] = f2bf(o);
                else
                    ((float*)Cout)[(size_t)(base_row + r) * 256 + col] = o;
            }
        }
    }
}

// ---------------------------------------------------------------------------
extern "C" void kernel_launch(void* const* d_in, const int* in_sizes, int n_in,
                              void* d_out, int out_size, void* d_ws, size_t ws_size,
                              hipStream_t stream) {
    const float* x  = (const float*)d_in[0];
    const int*   ei = (const int*)d_in[1];
    const float* W1 = (const float*)d_in[2];
    const float* b1 = (const float*)d_in[3];
    const float* W2 = (const float*)d_in[4];
    const float* b2 = (const float*)d_in[5];
    float* out = (float*)d_out;

    char* w = (char*)d_ws;
    float* dinv            = (float*)(w + 0x0);        // 128 KB
    int*   counts          = (int*)  (w + 0x20000);    // 128 KB
    int*   offs            = (int*)  (w + 0x60000);    // ~128 KB
    int*   csr             = (int*)  (w + 0x90000);    // 4 MB
    unsigned short* Wt1    = (unsigned short*)(w + 0x4A0000);   // 128 KB
    unsigned short* Wt2    = (unsigned short*)(w + 0x4C0000);   // 128 KB
    unsigned short* xb     = (unsigned short*)(w + 0x500000);   // 16 MB (y1)
    unsigned short* bufA   = (unsigned short*)(w + 0x1500000);  // 16 MB
    unsigned short* bufB   = (unsigned short*)(w + 0x2500000);  // 16 MB (y2)
    unsigned short* bufC   = (unsigned short*)(w + 0x3500000);  // 16 MB (ends 0x4500000)
    int*   rankp           = (int*)bufC;   // alias: rank buffer dead before bufC is written

    zero_kernel<<<32, 256, 0, stream>>>((int4*)counts);

    count_kernel<<<(B * E) / 256, 256, 0, stream>>>(ei, counts, rankp);
    scan_kernel<<<B, 1024, 0, stream>>>(counts, offs, dinv);
    fill_kernel<<<(B * E) / 256, 256, 0, stream>>>(ei, offs, rankp, csr);
    prep_w<<<512, 64, 0, stream>>>(W1, W2, Wt1, Wt2);
    xconv_kernel<<<8192, 256, 0, stream>>>(x, xb, dinv);   // y1 = dinv * x

    // layer 1: agg(y1) -> bufA ; y2 = dinv*relu(bufA@W1+b1) -> bufB
    agg_sum<<<8192, 256, 0, stream>>>(xb, bufA, csr, offs, dinv);
    gemm_mfma<true, true, true><<<1024, 256, 0, stream>>>(bufA, Wt1, b1, dinv, bufB);
    // layer 2: agg(y2) -> bufC ; bufC@W2+b2 -> out (f32)
    agg_sum<<<8192, 256, 0, stream>>>(bufB, bufC, csr, offs, dinv);
    gemm_mfma<false, false, false><<<1024, 256, 0, stream>>>(bufC, Wt2, b2, nullptr, out);
}

// Round 8
// 159.829 us; speedup vs baseline: 2.8761x; 1.0516x over previous
//
#include <hip/hip_runtime.h>

// Problem constants (from reference)
constexpr int B = 8;
constexpr int N = 4096;
constexpr int E = 131072;     // 2^17
constexpr int C = 256;
constexpr int BN_TOT = B * N; // 32768

typedef __attribute__((ext_vector_type(8))) short s16x8;
typedef __attribute__((ext_vector_type(4))) float f32x4;

__device__ __forceinline__ unsigned short f2bf(float f) {
    unsigned u = __float_as_uint(f);
    unsigned r = (u + 0x7FFFu + ((u >> 16) & 1u)) >> 16;   // RNE
    return (unsigned short)r;
}
__device__ __forceinline__ float b2f(unsigned short u) {
    return __uint_as_float(((unsigned)u) << 16);
}
// unpack 2 packed bf16 (u32) -> 2 f32: low ch = q<<16, high ch = q & 0xFFFF0000
__device__ __forceinline__ void acc2(float2& a, unsigned q) {
    a.x += __uint_as_float(q << 16);
    a.y += __uint_as_float(q & 0xFFFF0000u);
}
__device__ __forceinline__ float2 unpk(unsigned q) {
    return make_float2(__uint_as_float(q << 16), __uint_as_float(q & 0xFFFF0000u));
}

// ---------------------------------------------------------------------------
// K0: zero counts (runtime fillBuffer kernel is slow at tiny sizes)
__global__ __launch_bounds__(256) void zero_kernel(int4* __restrict__ p) {
    p[blockIdx.x * 256 + threadIdx.x] = make_int4(0, 0, 0, 0);
}

// ---------------------------------------------------------------------------
// K1: count in-degree per (graph, node); atomic return value IS the edge's
// rank within its dst bucket -> store packed (dst | rank<<12) for fill.
__global__ __launch_bounds__(256) void count_kernel(const int* __restrict__ ei,
                                                    int* __restrict__ counts,
                                                    int* __restrict__ rankp) {
    int bid = blockIdx.x;
    int g = bid & 7;
    int e = (bid >> 3) * 256 + threadIdx.x;       // [0, E)
    int dst = ei[(size_t)g * 2 * E + E + e];
    int r = atomicAdd(&counts[g * N + dst], 1);
    rankp[(size_t)g * E + e] = dst | (r << 12);   // rank < 2^17 fits
}

// ---------------------------------------------------------------------------
// K2: per-graph exclusive scan of counts -> CSR offsets; dinv = rsqrt(deg+1)
__global__ __launch_bounds__(1024) void scan_kernel(const int* __restrict__ counts,
                                                    int* __restrict__ offs,
                                                    float* __restrict__ dinv) {
    __shared__ int lds[1024];
    int b = blockIdx.x, t = threadIdx.x;
    int base = b * N + t * 4;
    int c0 = counts[base + 0];
    int c1 = counts[base + 1];
    int c2 = counts[base + 2];
    int c3 = counts[base + 3];
    lds[t] = c0 + c1 + c2 + c3;
    __syncthreads();
    for (int s = 1; s < 1024; s <<= 1) {
        int v = 0;
        if (t >= s) v = lds[t - s];
        __syncthreads();
        lds[t] += v;
        __syncthreads();
    }
    int excl = (t == 0) ? 0 : lds[t - 1];
    int ob = b * (N + 1) + t * 4;
    offs[ob + 0] = excl;
    offs[ob + 1] = excl + c0;
    offs[ob + 2] = excl + c0 + c1;
    offs[ob + 3] = excl + c0 + c1 + c2;
    if (t == 1023) offs[b * (N + 1) + N] = lds[1023];
    dinv[base + 0] = rsqrtf((float)(c0 + 1));
    dinv[base + 1] = rsqrtf((float)(c1 + 1));
    dinv[base + 2] = rsqrtf((float)(c2 + 1));
    dinv[base + 3] = rsqrtf((float)(c3 + 1));
}

// ---------------------------------------------------------------------------
// K3 (mega): block-range dispatch of three independent post-scan jobs:
//   [0,8192)      xconv: y1 = dinv[row]*x (f32->bf16), XCD-pinned
//   [8192,12288)  fill : scatter edge srcs into CSR (atomic-free)
//   [12288,12416) prep_w: W[K][N] f32 -> Wt[N][K] bf16 for both layers
__global__ __launch_bounds__(256) void mega_kernel(const int* __restrict__ ei,
                                                   const int* __restrict__ offs,
                                                   const int* __restrict__ rankp,
                                                   int* __restrict__ csr,
                                                   const float* __restrict__ x,
                                                   unsigned short* __restrict__ xb,
                                                   const float* __restrict__ dinv,
                                                   const float* __restrict__ W1,
                                                   const float* __restrict__ W2,
                                                   unsigned short* __restrict__ Wt1,
                                                   unsigned short* __restrict__ Wt2) {
    int bid = blockIdx.x;
    int tid = threadIdx.x;
    if (bid < 8192) {
        // --- xconv ---
        int g = bid & 7;
        int off = bid >> 3;                          // [0,1024)
        size_t base = (size_t)g * (N * C) + (size_t)off * 1024 + tid * 4;
        float dv = dinv[g * N + off * 4 + (tid >> 6)];
        float4 v = *(const float4*)(x + base);
        ushort4 o;
        o.x = f2bf(dv * v.x); o.y = f2bf(dv * v.y);
        o.z = f2bf(dv * v.z); o.w = f2bf(dv * v.w);
        *(ushort4*)(xb + base) = o;
    } else if (bid < 12288) {
        // --- fill ---
        int b2 = bid - 8192;
        int g = b2 & 7;
        int e = (b2 >> 3) * 256 + tid;
        int src = ei[(size_t)g * 2 * E + e];
        int pk = rankp[(size_t)g * E + e];
        int dst = pk & 4095;
        int r = pk >> 12;
        csr[(size_t)g * E + offs[g * (N + 1) + dst] + r] = src;
    } else {
        // --- prep_w ---
        int f = (bid - 12288) * 256 + tid;           // [0, 32768)
        int w = f >> 14;                             // 0: W1, 1: W2
        int idx = f & 16383;
        int n = idx >> 6;
        int ln = idx & 63;
        const float* W = w ? W2 : W1;
        unsigned short* Wt = w ? Wt2 : Wt1;
#pragma unroll
        for (int i = 0; i < 4; ++i) {
            int k = ln + i * 64;
            Wt[n * 256 + k] = f2bf(W[k * 256 + n]);
        }
    }
}

// ---------------------------------------------------------------------------
// K4: norm-free aggregation, TWO EDGES PER WAVE, 8-pair (16-edge) pipeline:
//   out[b,v,:] = dinv[v] * ( y[b,v,:] + sum_{u->v} y[b,u,:] )
// Lanes 0-31 take even edges, 32-63 odd; CSR pointer pre-offset by `half`
// so each lane loads ONE index per pair (no second load, no select).
// 16 B/lane (8 channels as 4 packed u32); u32 shift/mask unpack.
__global__ __launch_bounds__(256) void agg_sum(const unsigned short* __restrict__ in,
                                               unsigned short* __restrict__ out,
                                               const int* __restrict__ csr,
                                               const int* __restrict__ offs,
                                               const float* __restrict__ dinv) {
    int bid = blockIdx.x;
    int b = bid & 7;                      // XCD-pinned graph
    int v = (bid >> 3) * 4 + (threadIdx.x >> 6);
    int lane = threadIdx.x & 63;
    int half = lane >> 5;                 // 0: even edge of pair, 1: odd
    int hl = lane & 31;                   // channels [hl*8, hl*8+8)
    const unsigned short* inb = in + (size_t)b * (N * C);
    const char* base = (const char*)(inb + hl * 8);
    const int* cs2 = csr + (size_t)b * E + half;   // cs2[2*j] = edge (j,half)

    int s = offs[b * (N + 1) + v];
    int e = offs[b * (N + 1) + v + 1];
    const int* ip0 = cs2 + s;

    float2 acc[4];
    {   // self-loop term: lower half only (upper half zeros to avoid double count)
        uint4 xv = *(const uint4*)(inb + (size_t)v * C + hl * 8);
        if (half) {
            acc[0] = acc[1] = acc[2] = acc[3] = make_float2(0.f, 0.f);
        } else {
            acc[0] = unpk(xv.x); acc[1] = unpk(xv.y);
            acc[2] = unpk(xv.z); acc[3] = unpk(xv.w);
        }
    }

    int np = (e - s) >> 1;               // edge pairs
    int ip = 0;
    if (np >= 8) {
        int u[8];
#pragma unroll
        for (int j = 0; j < 8; ++j) u[j] = ip0[2 * j];
        for (; ip + 16 <= np; ip += 8) {
            uint4 f[8];
#pragma unroll
            for (int j = 0; j < 8; ++j)
                f[j] = *(const uint4*)(base + ((size_t)(unsigned)u[j] << 9));
#pragma unroll
            for (int j = 0; j < 8; ++j) u[j] = ip0[2 * (ip + 8 + j)];
#pragma unroll
            for (int j = 0; j < 8; ++j) {
                acc2(acc[0], f[j].x); acc2(acc[1], f[j].y);
                acc2(acc[2], f[j].z); acc2(acc[3], f[j].w);
            }
        }
        {   // drain last preloaded batch
            uint4 f[8];
#pragma unroll
            for (int j = 0; j < 8; ++j)
                f[j] = *(const uint4*)(base + ((size_t)(unsigned)u[j] << 9));
#pragma unroll
            for (int j = 0; j < 8; ++j) {
                acc2(acc[0], f[j].x); acc2(acc[1], f[j].y);
                acc2(acc[2], f[j].z); acc2(acc[3], f[j].w);
            }
            ip += 8;
        }
    }
    if (ip + 4 <= np) {                  // batched tail of 4 pairs
        int u[4];
#pragma unroll
        for (int j = 0; j < 4; ++j) u[j] = ip0[2 * (ip + j)];
        uint4 f[4];
#pragma unroll
        for (int j = 0; j < 4; ++j)
            f[j] = *(const uint4*)(base + ((size_t)(unsigned)u[j] << 9));
#pragma unroll
        for (int j = 0; j < 4; ++j) {
            acc2(acc[0], f[j].x); acc2(acc[1], f[j].y);
            acc2(acc[2], f[j].z); acc2(acc[3], f[j].w);
        }
        ip += 4;
    }
    for (; ip < np; ++ip) {
        int u = ip0[2 * ip];
        uint4 f = *(const uint4*)(base + ((size_t)(unsigned)u << 9));
        acc2(acc[0], f.x); acc2(acc[1], f.y); acc2(acc[2], f.z); acc2(acc[3], f.w);
    }
    if (((e - s) & 1) && !half) {        // odd tail edge: lower half only
        int u = ip0[2 * np];             // = cs[e-1] (half==0)
        uint4 f = *(const uint4*)(base + ((size_t)(unsigned)u << 9));
        acc2(acc[0], f.x); acc2(acc[1], f.y); acc2(acc[2], f.z); acc2(acc[3], f.w);
    }

    // combine halves
#pragma unroll
    for (int c = 0; c < 4; ++c) {
        acc[c].x += __shfl_xor(acc[c].x, 32, 64);
        acc[c].y += __shfl_xor(acc[c].y, 32, 64);
    }

    float dv = dinv[b * N + v];
    if (!half) {
        ushort4 o01, o23;
        o01.x = f2bf(dv * acc[0].x); o01.y = f2bf(dv * acc[0].y);
        o01.z = f2bf(dv * acc[1].x); o01.w = f2bf(dv * acc[1].y);
        o23.x = f2bf(dv * acc[2].x); o23.y = f2bf(dv * acc[2].y);
        o23.z = f2bf(dv * acc[3].x); o23.w = f2bf(dv * acc[3].y);
        unsigned short* op = out + ((size_t)b * N + v) * C + hl * 8;
        *(ushort4*)(op) = o01;
        *(ushort4*)(op + 4) = o23;
    }
}

// ---------------------------------------------------------------------------
// K5: bf16 MFMA GEMM: Cout[M,256] = A[M,256] @ W[256,256] (+bias, opt ReLU,
// opt row-scale by dinv). A bf16 row-major; Wt bf16 TRANSPOSED [N][K].
// 256 thr = 4 waves, tile 128x64, K-chunks of 64; LDS 24 KB -> 4 blocks/CU.
// LDS XOR-swizzled (byte ^= (row&7)<<4).
// C/D layout (HW-verified): col = lane&15, row = (lane>>4)*4 + reg.
template <bool RELU, bool BF16OUT, bool SCALE>
__global__ __launch_bounds__(256) void gemm_mfma(const unsigned short* __restrict__ A,
                                                 const unsigned short* __restrict__ Wt,
                                                 const float* __restrict__ bias,
                                                 const float* __restrict__ dinv,
                                                 void* __restrict__ Cout) {
    __shared__ __align__(16) char lds[24576];
    char* AsB = lds;            // 16 KB: [128 m][64 k] bf16, swizzled
    char* WsB = lds + 16384;    //  8 KB: [64 n][64 k] bf16, swizzled

    int tid = threadIdx.x;
    int bid = blockIdx.x;
    int g = bid & 7;                 // XCD-pinned graph
    int i = bid >> 3;                // [0,128)
    int mloc = i >> 2;               // [0,32)
    int nb = i & 3;                  // [0,4)
    int bm = g * 4096 + mloc * 128;
    int bn = nb * 64;

    const int l = tid & 63;
    const int w = tid >> 6;
    const int lr = l & 15;
    const int lg = l >> 4;

    f32x4 acc[2][4] = {};

    for (int kc = 0; kc < 4; ++kc) {
        __syncthreads();             // protect LDS from prior-iter readers
        // Stage A chunk: [128 rows][64 k] = 1024 x 16B chunks (4/thread).
#pragma unroll
        for (int c = 0; c < 4; ++c) {
            int f = tid + c * 256;
            int row = f >> 3;
            int slot = f & 7;
            s16x8 vv = *(const s16x8*)(A + (size_t)(bm + row) * 256 + kc * 64 + slot * 8);
            *(s16x8*)(AsB + row * 128 + ((slot * 16) ^ ((row & 7) << 4))) = vv;
        }
        // Stage W chunk: [64 rows][64 k] = 512 x 16B chunks (2/thread).
#pragma unroll
        for (int c = 0; c < 2; ++c) {
            int f = tid + c * 256;
            int r = f >> 3;
            int slot = f & 7;
            s16x8 vv = *(const s16x8*)(Wt + (size_t)(bn + r) * 256 + kc * 64 + slot * 8);
            *(s16x8*)(WsB + r * 128 + ((slot * 16) ^ ((r & 7) << 4))) = vv;
        }
        __syncthreads();

#pragma unroll
        for (int ks = 0; ks < 2; ++ks) {
            s16x8 af[2];
#pragma unroll
            for (int m = 0; m < 2; ++m) {
                int row = w * 32 + m * 16 + lr;
                int bir = ks * 64 + lg * 16;          // byte within 128B row
                af[m] = *(const s16x8*)(AsB + row * 128 + (bir ^ ((row & 7) << 4)));
            }
            s16x8 wf[4];
#pragma unroll
            for (int n = 0; n < 4; ++n) {
                int cidx = n * 16 + lr;
                int bir = ks * 64 + lg * 16;
                wf[n] = *(const s16x8*)(WsB + cidx * 128 + (bir ^ ((cidx & 7) << 4)));
            }
#pragma unroll
            for (int m = 0; m < 2; ++m)
#pragma unroll
                for (int n = 0; n < 4; ++n)
                    acc[m][n] = __builtin_amdgcn_mfma_f32_16x16x32_bf16(af[m], wf[n], acc[m][n], 0, 0, 0);
        }
    }

    // Epilogue: D col = lane&15, row = (lane>>4)*4 + reg
#pragma unroll
    for (int m = 0; m < 2; ++m) {
        int base_row = bm + w * 32 + m * 16 + lg * 4;
        float4 dv4 = make_float4(1.f, 1.f, 1.f, 1.f);
        if (SCALE) dv4 = *(const float4*)(dinv + base_row);
        float dvr[4] = {dv4.x, dv4.y, dv4.z, dv4.w};
#pragma unroll
        for (int n = 0; n < 4; ++n) {
            int col = bn + n * 16 + lr;
            float bb = bias[col];
            f32x4 v = acc[m][n];
#pragma unroll
            for (int r = 0; r < 4; ++r) {
                float o = v[r] + bb;
                if (RELU) o = fmaxf(o, 0.f);
                if (SCALE) o *= dvr[r];
                if (BF16OUT)
                    ((unsigned short*)Cout)[(size_t)(base_row + r) * 256 + col] = f2bf(o);
                else
                    ((float*)Cout)[(size_t)(base_row + r) * 256 + col] = o;
            }
        }
    }
}

// ---------------------------------------------------------------------------
extern "C" void kernel_launch(void* const* d_in, const int* in_sizes, int n_in,
                              void* d_out, int out_size, void* d_ws, size_t ws_size,
                              hipStream_t stream) {
    const float* x  = (const float*)d_in[0];
    const int*   ei = (const int*)d_in[1];
    const float* W1 = (const float*)d_in[2];
    const float* b1 = (const float*)d_in[3];
    const float* W2 = (const float*)d_in[4];
    const float* b2 = (const float*)d_in[5];
    float* out = (float*)d_out;

    char* w = (char*)d_ws;
    float* dinv            = (float*)(w + 0x0);        // 128 KB
    int*   counts          = (int*)  (w + 0x20000);    // 128 KB
    int*   offs            = (int*)  (w + 0x60000);    // ~128 KB
    int*   csr             = (int*)  (w + 0x90000);    // 4 MB
    unsigned short* Wt1    = (unsigned short*)(w + 0x4A0000);   // 128 KB
    unsigned short* Wt2    = (unsigned short*)(w + 0x4C0000);   // 128 KB
    unsigned short* xb     = (unsigned short*)(w + 0x500000);   // 16 MB (y1)
    unsigned short* bufA   = (unsigned short*)(w + 0x1500000);  // 16 MB
    unsigned short* bufB   = (unsigned short*)(w + 0x2500000);  // 16 MB (y2)
    unsigned short* bufC   = (unsigned short*)(w + 0x3500000);  // 16 MB (ends 0x4500000)
    int*   rankp           = (int*)bufC;   // alias: rank buffer dead before bufC is written

    zero_kernel<<<32, 256, 0, stream>>>((int4*)counts);
    count_kernel<<<(B * E) / 256, 256, 0, stream>>>(ei, counts, rankp);
    scan_kernel<<<B, 1024, 0, stream>>>(counts, offs, dinv);
    mega_kernel<<<12416, 256, 0, stream>>>(ei, offs, rankp, csr,
                                           x, xb, dinv, W1, W2, Wt1, Wt2);

    // layer 1: agg(y1) -> bufA ; y2 = dinv*relu(bufA@W1+b1) -> bufB
    agg_sum<<<8192, 256, 0, stream>>>(xb, bufA, csr, offs, dinv);
    gemm_mfma<true, true, true><<<1024, 256, 0, stream>>>(bufA, Wt1, b1, dinv, bufB);
    // layer 2: agg(y2) -> bufC ; bufC@W2+b2 -> out (f32)
    agg_sum<<<8192, 256, 0, stream>>>(bufB, bufC, csr, offs, dinv);
    gemm_mfma<false, false, false><<<1024, 256, 0, stream>>>(bufC, Wt2, b2, nullptr, out);
}